// Round 1
// baseline (13275.185 us; speedup 1.0000x reference)
//
#include <hip/hip_runtime.h>
#include <math.h>

#define N_NODES 100000
#define F_IN    128
#define H1      8
#define C1      16
#define D1      128   // H1*C1
#define NCLS    40
#define NEG     0.2f

// ---------------- layer 1 GEMM: h1[N,128] = x[N,128] @ W1[128,128] ----------
__global__ void gemm1_kernel(const float* __restrict__ x,
                             const float* __restrict__ W,
                             float* __restrict__ h)
{
    __shared__ float xs[16][128];
    const int row0 = blockIdx.x * 16;
    const int t = threadIdx.x;
#pragma unroll
    for (int i = 0; i < 8; ++i) {
        int idx = t + i * 256;          // 0..2047
        int r = idx >> 7, c = idx & 127;
        xs[r][c] = x[(size_t)(row0 + r) * 128 + c];
    }
    __syncthreads();
    const int col = t & 127;
    const int half = t >> 7;            // 0 or 1; rows = half + 2*i
    float acc[8] = {0.f, 0.f, 0.f, 0.f, 0.f, 0.f, 0.f, 0.f};
    for (int k = 0; k < 128; ++k) {
        float w = W[k * 128 + col];
#pragma unroll
        for (int i = 0; i < 8; ++i)
            acc[i] += xs[half + 2 * i][k] * w;
    }
#pragma unroll
    for (int i = 0; i < 8; ++i)
        h[(size_t)(row0 + half + 2 * i) * 128 + col] = acc[i];
}

// ---------------- per-node attention logits, layer 1 ------------------------
__global__ void logits1_kernel(const float* __restrict__ h,
                               const float* __restrict__ a_src,
                               const float* __restrict__ a_dst,
                               float* __restrict__ ssrc,
                               float* __restrict__ sdst)
{
    int id = blockIdx.x * blockDim.x + threadIdx.x;
    if (id >= N_NODES * H1) return;
    int n = id >> 3, hh = id & 7;
    const float* hp = h + (size_t)n * D1 + hh * C1;
    float as = 0.f, ad = 0.f;
#pragma unroll
    for (int c = 0; c < C1; ++c) {
        float v = hp[c];
        as += v * a_src[hh * C1 + c];
        ad += v * a_dst[hh * C1 + c];
    }
    ssrc[id] = as;
    sdst[id] = ad;
}

// ---------------- edge scatter pass, layer 1 --------------------------------
// one thread per (edge, head); accumulates unnormalized weighted sum + denom
__global__ void edge1_kernel(const int* __restrict__ ei, int E,
                             const float* __restrict__ h,
                             const float* __restrict__ ssrc,
                             const float* __restrict__ sdst,
                             float* __restrict__ acc,
                             float* __restrict__ denom)
{
    long long id = (long long)blockIdx.x * blockDim.x + threadIdx.x;
    long long tot = (long long)(E + N_NODES) * H1;
    if (id >= tot) return;
    int e = (int)(id >> 3);
    int hh = (int)(id & 7);
    int s, d;
    if (e < E) { s = ei[e]; d = ei[E + e]; }
    else       { s = d = e - E; }                 // self-loop
    float lg = ssrc[s * H1 + hh] + sdst[d * H1 + hh];
    lg = lg >= 0.f ? lg : NEG * lg;               // leaky_relu
    float w = __expf(lg);
    atomicAdd(&denom[d * H1 + hh], w);
    const float* hp = h + (size_t)s * D1 + hh * C1;
    float* ap = acc + (size_t)d * D1 + hh * C1;
#pragma unroll
    for (int c = 0; c < C1; ++c)
        atomicAdd(&ap[c], w * hp[c]);
}

// ---------------- finalize layer 1: divide, +bias, relu (in place) ----------
__global__ void finalize1_kernel(float* __restrict__ acc,
                                 const float* __restrict__ denom,
                                 const float* __restrict__ b1)
{
    int id = blockIdx.x * blockDim.x + threadIdx.x;
    if (id >= N_NODES * D1) return;
    int n = id >> 7, col = id & 127;
    float v = acc[id] / (denom[n * H1 + (col >> 4)] + 1e-16f) + b1[col];
    acc[id] = v > 0.f ? v : 0.f;
}

// ---------------- layer 2 GEMM: h2[N,40] = hrelu[N,128] @ W2[128,40] --------
__global__ void gemm2_kernel(const float* __restrict__ h,
                             const float* __restrict__ W2,
                             float* __restrict__ h2)
{
    int id = blockIdx.x * blockDim.x + threadIdx.x;
    if (id >= N_NODES * NCLS) return;
    int n = id / NCLS, c = id % NCLS;
    const float* hr = h + (size_t)n * D1;
    float acc = 0.f;
#pragma unroll 8
    for (int k = 0; k < D1; ++k)
        acc += hr[k] * W2[k * NCLS + c];
    h2[id] = acc;
}

// ---------------- per-node attention logits, layer 2 ------------------------
__global__ void logits2_kernel(const float* __restrict__ h2,
                               const float* __restrict__ a_src,
                               const float* __restrict__ a_dst,
                               float* __restrict__ ssrc,
                               float* __restrict__ sdst)
{
    int n = blockIdx.x * blockDim.x + threadIdx.x;
    if (n >= N_NODES) return;
    const float* hp = h2 + (size_t)n * NCLS;
    float as = 0.f, ad = 0.f;
#pragma unroll
    for (int c = 0; c < NCLS; ++c) {
        float v = hp[c];
        as += v * a_src[c];
        ad += v * a_dst[c];
    }
    ssrc[n] = as;
    sdst[n] = ad;
}

// ---------------- edge scatter pass, layer 2 (1 head, 40 channels) ----------
// 8 lanes per edge; lane L handles channels L, L+8, ...
__global__ void edge2_kernel(const int* __restrict__ ei, int E,
                             const float* __restrict__ h2,
                             const float* __restrict__ ssrc,
                             const float* __restrict__ sdst,
                             float* __restrict__ acc,
                             float* __restrict__ denom)
{
    long long id = (long long)blockIdx.x * blockDim.x + threadIdx.x;
    long long tot = (long long)(E + N_NODES) * 8;
    if (id >= tot) return;
    int e = (int)(id >> 3);
    int lane = (int)(id & 7);
    int s, d;
    if (e < E) { s = ei[e]; d = ei[E + e]; }
    else       { s = d = e - E; }
    float lg = ssrc[s] + sdst[d];
    lg = lg >= 0.f ? lg : NEG * lg;
    float w = __expf(lg);
    if (lane == 0) atomicAdd(&denom[d], w);
    const float* hp = h2 + (size_t)s * NCLS;
    float* ap = acc + (size_t)d * NCLS;
    for (int c = lane; c < NCLS; c += 8)
        atomicAdd(&ap[c], w * hp[c]);
}

// ---------------- finalize layer 2: divide, +bias, log_softmax --------------
// one 64-lane wave per node (lanes 0..39 hold channels)
__global__ void finalize2_kernel(const float* __restrict__ acc,
                                 const float* __restrict__ denom,
                                 const float* __restrict__ b2,
                                 float* __restrict__ out)
{
    int wave = (blockIdx.x * blockDim.x + threadIdx.x) >> 6;
    int lane = threadIdx.x & 63;
    if (wave >= N_NODES) return;
    float logit = 0.f;
    float v = -INFINITY;
    if (lane < NCLS) {
        logit = acc[(size_t)wave * NCLS + lane] / (denom[wave] + 1e-16f) + b2[lane];
        v = logit;
    }
#pragma unroll
    for (int o = 32; o > 0; o >>= 1)
        v = fmaxf(v, __shfl_xor(v, o));
    float m = v;
    float ex = (lane < NCLS) ? __expf(logit - m) : 0.f;
#pragma unroll
    for (int o = 32; o > 0; o >>= 1)
        ex += __shfl_xor(ex, o);
    float lse = __logf(ex) + m;
    if (lane < NCLS)
        out[(size_t)wave * NCLS + lane] = logit - lse;
}

extern "C" void kernel_launch(void* const* d_in, const int* in_sizes, int n_in,
                              void* d_out, int out_size, void* d_ws, size_t ws_size,
                              hipStream_t stream)
{
    const float* x   = (const float*)d_in[0];
    const int*   ei  = (const int*)  d_in[1];
    const float* W1  = (const float*)d_in[2];
    const float* as1 = (const float*)d_in[3];
    const float* ad1 = (const float*)d_in[4];
    const float* b1  = (const float*)d_in[5];
    const float* W2  = (const float*)d_in[6];
    const float* as2 = (const float*)d_in[7];
    const float* ad2 = (const float*)d_in[8];
    const float* b2  = (const float*)d_in[9];
    float* out = (float*)d_out;
    const int E = in_sizes[1] / 2;

    float* ws = (float*)d_ws;
    size_t off = 0;
    float* h1   = ws + off; off += (size_t)N_NODES * D1;
    float* ss1  = ws + off; off += (size_t)N_NODES * H1;
    float* sd1  = ws + off; off += (size_t)N_NODES * H1;
    float* h2   = ws + off; off += (size_t)N_NODES * NCLS;
    float* ss2  = ws + off; off += N_NODES;
    float* sd2  = ws + off; off += N_NODES;
    float* zbase = ws + off;
    float* acc1 = ws + off; off += (size_t)N_NODES * D1;
    float* den1 = ws + off; off += (size_t)N_NODES * H1;
    float* acc2 = ws + off; off += (size_t)N_NODES * NCLS;
    float* den2 = ws + off; off += N_NODES;
    size_t zbytes = (size_t)(N_NODES * (D1 + H1 + NCLS + 1)) * sizeof(float);
    hipMemsetAsync(zbase, 0, zbytes, stream);

    gemm1_kernel<<<N_NODES / 16, 256, 0, stream>>>(x, W1, h1);
    logits1_kernel<<<(N_NODES * H1 + 255) / 256, 256, 0, stream>>>(h1, as1, ad1, ss1, sd1);
    long long tot1 = (long long)(E + N_NODES) * H1;
    edge1_kernel<<<(int)((tot1 + 255) / 256), 256, 0, stream>>>(ei, E, h1, ss1, sd1, acc1, den1);
    finalize1_kernel<<<(N_NODES * D1 + 255) / 256, 256, 0, stream>>>(acc1, den1, b1);
    gemm2_kernel<<<(N_NODES * NCLS + 255) / 256, 256, 0, stream>>>(acc1, W2, h2);
    logits2_kernel<<<(N_NODES + 255) / 256, 256, 0, stream>>>(h2, as2, ad2, ss2, sd2);
    long long tot2 = (long long)(E + N_NODES) * 8;
    edge2_kernel<<<(int)((tot2 + 255) / 256), 256, 0, stream>>>(ei, E, h2, ss2, sd2, acc2, den2);
    finalize2_kernel<<<(N_NODES + 3) / 4, 256, 0, stream>>>(acc2, den2, b2, out);
}

// Round 2
// 853.150 us; speedup vs baseline: 15.5602x; 15.5602x over previous
//
#include <hip/hip_runtime.h>
#include <math.h>

#define N_NODES 100000
#define F_IN    128
#define H1      8
#define C1      16
#define D1      128   // H1*C1
#define NCLS    40
#define NEG     0.2f

// ---------------- layer 1 GEMM: h1[N,128] = x[N,128] @ W1[128,128] ----------
__global__ void gemm1_kernel(const float* __restrict__ x,
                             const float* __restrict__ W,
                             float* __restrict__ h)
{
    __shared__ float xs[16][128];
    const int row0 = blockIdx.x * 16;
    const int t = threadIdx.x;
#pragma unroll
    for (int i = 0; i < 8; ++i) {
        int idx = t + i * 256;          // 0..2047
        int r = idx >> 7, c = idx & 127;
        xs[r][c] = x[(size_t)(row0 + r) * 128 + c];
    }
    __syncthreads();
    const int col = t & 127;
    const int half = t >> 7;            // 0 or 1; rows = half + 2*i
    float acc[8] = {0.f, 0.f, 0.f, 0.f, 0.f, 0.f, 0.f, 0.f};
    for (int k = 0; k < 128; ++k) {
        float w = W[k * 128 + col];
#pragma unroll
        for (int i = 0; i < 8; ++i)
            acc[i] += xs[half + 2 * i][k] * w;
    }
#pragma unroll
    for (int i = 0; i < 8; ++i)
        h[(size_t)(row0 + half + 2 * i) * 128 + col] = acc[i];
}

// ---------------- per-node attention logits, layer 1 ------------------------
__global__ void logits1_kernel(const float* __restrict__ h,
                               const float* __restrict__ a_src,
                               const float* __restrict__ a_dst,
                               float* __restrict__ ssrc,
                               float* __restrict__ sdst)
{
    int id = blockIdx.x * blockDim.x + threadIdx.x;
    if (id >= N_NODES * H1) return;
    int n = id >> 3, hh = id & 7;
    const float* hp = h + (size_t)n * D1 + hh * C1;
    float as = 0.f, ad = 0.f;
#pragma unroll
    for (int c = 0; c < C1; ++c) {
        float v = hp[c];
        as += v * a_src[hh * C1 + c];
        ad += v * a_dst[hh * C1 + c];
    }
    ssrc[id] = as;
    sdst[id] = ad;
}

// ---------------- CSR build: histogram by dst -------------------------------
__global__ void count_kernel(const int* __restrict__ ei, int E,
                             int* __restrict__ deg)
{
    int e = blockIdx.x * blockDim.x + threadIdx.x;
    if (e < E) atomicAdd(&deg[ei[E + e]], 1);
}

// block-local inclusive scan (256/block) + block sums
__global__ void scan1_kernel(const int* __restrict__ deg,
                             int* __restrict__ incl,
                             int* __restrict__ bsum)
{
    __shared__ int tmp[256];
    int i = blockIdx.x * 256 + threadIdx.x;
    int v = (i < N_NODES) ? deg[i] : 0;
    tmp[threadIdx.x] = v;
    __syncthreads();
    for (int o = 1; o < 256; o <<= 1) {
        int t = (threadIdx.x >= (unsigned)o) ? tmp[threadIdx.x - o] : 0;
        __syncthreads();
        tmp[threadIdx.x] += t;
        __syncthreads();
    }
    if (i < N_NODES) incl[i] = tmp[threadIdx.x];
    if (threadIdx.x == 255) bsum[blockIdx.x] = tmp[255];
}

// exclusive scan of block sums (nb <= 512), single block
__global__ void scan2_kernel(int* __restrict__ bsum, int nb)
{
    __shared__ int tmp[512];
    int v = (threadIdx.x < (unsigned)nb) ? bsum[threadIdx.x] : 0;
    tmp[threadIdx.x] = v;
    __syncthreads();
    for (int o = 1; o < 512; o <<= 1) {
        int t = (threadIdx.x >= (unsigned)o) ? tmp[threadIdx.x - o] : 0;
        __syncthreads();
        tmp[threadIdx.x] += t;
        __syncthreads();
    }
    if (threadIdx.x < (unsigned)nb) bsum[threadIdx.x] = tmp[threadIdx.x] - v;
}

// offsets[i+1] = incl[i] + bsum[block]; offsets[0] = 0
__global__ void scan3_kernel(const int* __restrict__ incl,
                             const int* __restrict__ bsum,
                             int* __restrict__ offsets)
{
    int i = blockIdx.x * 256 + threadIdx.x;
    if (i < N_NODES) offsets[i + 1] = incl[i] + bsum[blockIdx.x];
    if (i == 0) offsets[0] = 0;
}

__global__ void scatter_kernel(const int* __restrict__ ei, int E,
                               const int* __restrict__ offsets,
                               int* __restrict__ cursor,
                               int* __restrict__ srcs)
{
    int e = blockIdx.x * blockDim.x + threadIdx.x;
    if (e >= E) return;
    int s = ei[e], d = ei[E + e];
    int pos = offsets[d] + atomicAdd(&cursor[d], 1);
    srcs[pos] = s;
}

// ---------------- layer 1 gather: one wave per dst node ---------------------
// lane l owns channels l and l+64 (heads l>>4 and 4+(l>>4)).
// fuses: edge softmax-weight, weighted sum, divide, +bias, relu.
__global__ void gather1_kernel(const float* __restrict__ h,
                               const float* __restrict__ ssrc,
                               const float* __restrict__ sdst,
                               const int* __restrict__ offsets,
                               const int* __restrict__ srcs,
                               const float* __restrict__ b1,
                               float* __restrict__ out)
{
    int d = (blockIdx.x * blockDim.x + threadIdx.x) >> 6;
    int lane = threadIdx.x & 63;
    if (d >= N_NODES) return;
    const int c0 = lane, c1 = lane + 64;
    const int ha = lane >> 4;          // head for c0: 0..3
    const int hb = ha + 4;             // head for c1: 4..7
    const float sd0 = sdst[d * H1 + ha];
    const float sd1 = sdst[d * H1 + hb];
    float acc0 = 0.f, acc1 = 0.f, ws0 = 0.f, ws1 = 0.f;

    // self-loop
    {
        float l0 = ssrc[d * H1 + ha] + sd0; l0 = l0 >= 0.f ? l0 : NEG * l0;
        float l1 = ssrc[d * H1 + hb] + sd1; l1 = l1 >= 0.f ? l1 : NEG * l1;
        float w0 = __expf(l0), w1 = __expf(l1);
        acc0 += w0 * h[(size_t)d * D1 + c0];
        acc1 += w1 * h[(size_t)d * D1 + c1];
        ws0 += w0; ws1 += w1;
    }
    const int beg = offsets[d], end = offsets[d + 1];
    for (int k = beg; k < end; ++k) {
        int s = srcs[k];
        float l0 = ssrc[s * H1 + ha] + sd0; l0 = l0 >= 0.f ? l0 : NEG * l0;
        float l1 = ssrc[s * H1 + hb] + sd1; l1 = l1 >= 0.f ? l1 : NEG * l1;
        float w0 = __expf(l0), w1 = __expf(l1);
        acc0 += w0 * h[(size_t)s * D1 + c0];
        acc1 += w1 * h[(size_t)s * D1 + c1];
        ws0 += w0; ws1 += w1;
    }
    float v0 = acc0 / (ws0 + 1e-16f) + b1[c0];
    float v1 = acc1 / (ws1 + 1e-16f) + b1[c1];
    out[(size_t)d * D1 + c0] = v0 > 0.f ? v0 : 0.f;
    out[(size_t)d * D1 + c1] = v1 > 0.f ? v1 : 0.f;
}

// ---------------- layer 2 GEMM: h2[N,40] = hrelu[N,128] @ W2[128,40] --------
__global__ void gemm2_kernel(const float* __restrict__ h,
                             const float* __restrict__ W2,
                             float* __restrict__ h2)
{
    int id = blockIdx.x * blockDim.x + threadIdx.x;
    if (id >= N_NODES * NCLS) return;
    int n = id / NCLS, c = id % NCLS;
    const float* hr = h + (size_t)n * D1;
    float acc = 0.f;
#pragma unroll 8
    for (int k = 0; k < D1; ++k)
        acc += hr[k] * W2[k * NCLS + c];
    h2[id] = acc;
}

// ---------------- per-node attention logits, layer 2 ------------------------
__global__ void logits2_kernel(const float* __restrict__ h2,
                               const float* __restrict__ a_src,
                               const float* __restrict__ a_dst,
                               float* __restrict__ ssrc,
                               float* __restrict__ sdst)
{
    int n = blockIdx.x * blockDim.x + threadIdx.x;
    if (n >= N_NODES) return;
    const float* hp = h2 + (size_t)n * NCLS;
    float as = 0.f, ad = 0.f;
#pragma unroll
    for (int c = 0; c < NCLS; ++c) {
        float v = hp[c];
        as += v * a_src[c];
        ad += v * a_dst[c];
    }
    ssrc[n] = as;
    sdst[n] = ad;
}

// ---------------- layer 2 gather + log_softmax: one wave per node -----------
__global__ void gather2_kernel(const float* __restrict__ h2,
                               const float* __restrict__ ssrc,
                               const float* __restrict__ sdst,
                               const int* __restrict__ offsets,
                               const int* __restrict__ srcs,
                               const float* __restrict__ b2,
                               float* __restrict__ out)
{
    int d = (blockIdx.x * blockDim.x + threadIdx.x) >> 6;
    int lane = threadIdx.x & 63;
    if (d >= N_NODES) return;
    const float sd = sdst[d];
    float acc = 0.f, ws = 0.f;
    // self-loop
    {
        float lg = ssrc[d] + sd; lg = lg >= 0.f ? lg : NEG * lg;
        float w = __expf(lg);
        if (lane < NCLS) acc += w * h2[(size_t)d * NCLS + lane];
        ws += w;
    }
    const int beg = offsets[d], end = offsets[d + 1];
    for (int k = beg; k < end; ++k) {
        int s = srcs[k];
        float lg = ssrc[s] + sd; lg = lg >= 0.f ? lg : NEG * lg;
        float w = __expf(lg);
        if (lane < NCLS) acc += w * h2[(size_t)s * NCLS + lane];
        ws += w;
    }
    float logit = 0.f, v = -INFINITY;
    if (lane < NCLS) {
        logit = acc / (ws + 1e-16f) + b2[lane];
        v = logit;
    }
#pragma unroll
    for (int o = 32; o > 0; o >>= 1)
        v = fmaxf(v, __shfl_xor(v, o));
    float m = v;
    float ex = (lane < NCLS) ? __expf(logit - m) : 0.f;
#pragma unroll
    for (int o = 32; o > 0; o >>= 1)
        ex += __shfl_xor(ex, o);
    float lse = __logf(ex) + m;
    if (lane < NCLS)
        out[(size_t)d * NCLS + lane] = logit - lse;
}

extern "C" void kernel_launch(void* const* d_in, const int* in_sizes, int n_in,
                              void* d_out, int out_size, void* d_ws, size_t ws_size,
                              hipStream_t stream)
{
    const float* x   = (const float*)d_in[0];
    const int*   ei  = (const int*)  d_in[1];
    const float* W1  = (const float*)d_in[2];
    const float* as1 = (const float*)d_in[3];
    const float* ad1 = (const float*)d_in[4];
    const float* b1  = (const float*)d_in[5];
    const float* W2  = (const float*)d_in[6];
    const float* as2 = (const float*)d_in[7];
    const float* ad2 = (const float*)d_in[8];
    const float* b2  = (const float*)d_in[9];
    float* out = (float*)d_out;
    const int E = in_sizes[1] / 2;

    float* ws = (float*)d_ws;
    size_t off = 0;
    float* h1   = ws + off; off += (size_t)N_NODES * D1;
    float* h1r  = ws + off; off += (size_t)N_NODES * D1;
    float* ss1  = ws + off; off += (size_t)N_NODES * H1;
    float* sd1  = ws + off; off += (size_t)N_NODES * H1;
    float* h2   = ws + off; off += (size_t)N_NODES * NCLS;
    float* ss2  = ws + off; off += N_NODES;
    float* sd2  = ws + off; off += N_NODES;
    int* ib = (int*)(ws + off);
    size_t ioff = 0;
    int* deg     = ib + ioff; ioff += N_NODES;      // must be zeroed
    int* cursor  = ib + ioff; ioff += N_NODES;      // must be zeroed
    int* incl    = ib + ioff; ioff += N_NODES;
    int* offsets = ib + ioff; ioff += N_NODES + 1;
    int* bsum    = ib + ioff; ioff += 512;
    int* srcs    = ib + ioff; ioff += E;

    // zero only deg + cursor (adjacent)
    hipMemsetAsync(deg, 0, (size_t)2 * N_NODES * sizeof(int), stream);

    const int nb = (N_NODES + 255) / 256;           // 391
    // CSR build
    count_kernel<<<(E + 255) / 256, 256, 0, stream>>>(ei, E, deg);
    scan1_kernel<<<nb, 256, 0, stream>>>(deg, incl, bsum);
    scan2_kernel<<<1, 512, 0, stream>>>(bsum, nb);
    scan3_kernel<<<nb, 256, 0, stream>>>(incl, bsum, offsets);
    scatter_kernel<<<(E + 255) / 256, 256, 0, stream>>>(ei, E, offsets, cursor, srcs);

    // layer 1
    gemm1_kernel<<<N_NODES / 16, 256, 0, stream>>>(x, W1, h1);
    logits1_kernel<<<(N_NODES * H1 + 255) / 256, 256, 0, stream>>>(h1, as1, ad1, ss1, sd1);
    gather1_kernel<<<(N_NODES * 64 + 255) / 256, 256, 0, stream>>>(h1, ss1, sd1, offsets, srcs, b1, h1r);

    // layer 2
    gemm2_kernel<<<(N_NODES * NCLS + 255) / 256, 256, 0, stream>>>(h1r, W2, h2);
    logits2_kernel<<<(N_NODES + 255) / 256, 256, 0, stream>>>(h2, as2, ad2, ss2, sd2);
    gather2_kernel<<<(N_NODES * 64 + 255) / 256, 256, 0, stream>>>(h2, ss2, sd2, offsets, srcs, b2, out);
}

// Round 3
// 634.974 us; speedup vs baseline: 20.9066x; 1.3436x over previous
//
#include <hip/hip_runtime.h>
#include <math.h>

#define N_NODES 100000
#define F_IN    128
#define H1      8
#define C1      16
#define D1      128   // H1*C1
#define NCLS    40
#define NEG     0.2f

// ---------------- layer 1 GEMM: h1[N,128] = x[N,128] @ W1[128,128] ----------
__global__ void gemm1_kernel(const float* __restrict__ x,
                             const float* __restrict__ W,
                             float* __restrict__ h)
{
    __shared__ float xs[16][128];
    const int row0 = blockIdx.x * 16;
    const int t = threadIdx.x;
#pragma unroll
    for (int i = 0; i < 8; ++i) {
        int idx = t + i * 256;          // 0..2047
        int r = idx >> 7, c = idx & 127;
        xs[r][c] = x[(size_t)(row0 + r) * 128 + c];
    }
    __syncthreads();
    const int col = t & 127;
    const int half = t >> 7;            // 0 or 1; rows = half + 2*i
    float acc[8] = {0.f, 0.f, 0.f, 0.f, 0.f, 0.f, 0.f, 0.f};
    for (int k = 0; k < 128; ++k) {
        float w = W[k * 128 + col];
#pragma unroll
        for (int i = 0; i < 8; ++i)
            acc[i] += xs[half + 2 * i][k] * w;
    }
#pragma unroll
    for (int i = 0; i < 8; ++i)
        h[(size_t)(row0 + half + 2 * i) * 128 + col] = acc[i];
}

// ---------------- per-node attention logits, layer 1 ------------------------
__global__ void logits1_kernel(const float* __restrict__ h,
                               const float* __restrict__ a_src,
                               const float* __restrict__ a_dst,
                               float* __restrict__ ssrc,
                               float* __restrict__ sdst)
{
    int id = blockIdx.x * blockDim.x + threadIdx.x;
    if (id >= N_NODES * H1) return;
    int n = id >> 3, hh = id & 7;
    const float* hp = h + (size_t)n * D1 + hh * C1;
    float as = 0.f, ad = 0.f;
#pragma unroll
    for (int c = 0; c < C1; ++c) {
        float v = hp[c];
        as += v * a_src[hh * C1 + c];
        ad += v * a_dst[hh * C1 + c];
    }
    ssrc[id] = as;
    sdst[id] = ad;
}

// ---------------- CSR build: histogram by dst, saving each edge's rank ------
__global__ void count_kernel(const int* __restrict__ ei, int E,
                             int* __restrict__ deg,
                             int* __restrict__ rank)
{
    int e = blockIdx.x * blockDim.x + threadIdx.x;
    if (e < E) rank[e] = atomicAdd(&deg[ei[E + e]], 1);
}

// block-local inclusive scan (256/block) + block sums
__global__ void scan1_kernel(const int* __restrict__ deg,
                             int* __restrict__ incl,
                             int* __restrict__ bsum)
{
    __shared__ int tmp[256];
    int i = blockIdx.x * 256 + threadIdx.x;
    int v = (i < N_NODES) ? deg[i] : 0;
    tmp[threadIdx.x] = v;
    __syncthreads();
    for (int o = 1; o < 256; o <<= 1) {
        int t = (threadIdx.x >= (unsigned)o) ? tmp[threadIdx.x - o] : 0;
        __syncthreads();
        tmp[threadIdx.x] += t;
        __syncthreads();
    }
    if (i < N_NODES) incl[i] = tmp[threadIdx.x];
    if (threadIdx.x == 255) bsum[blockIdx.x] = tmp[255];
}

// exclusive scan of block sums (nb <= 512), single block
__global__ void scan2_kernel(int* __restrict__ bsum, int nb)
{
    __shared__ int tmp[512];
    int v = (threadIdx.x < (unsigned)nb) ? bsum[threadIdx.x] : 0;
    tmp[threadIdx.x] = v;
    __syncthreads();
    for (int o = 1; o < 512; o <<= 1) {
        int t = (threadIdx.x >= (unsigned)o) ? tmp[threadIdx.x - o] : 0;
        __syncthreads();
        tmp[threadIdx.x] += t;
        __syncthreads();
    }
    if (threadIdx.x < (unsigned)nb) bsum[threadIdx.x] = tmp[threadIdx.x] - v;
}

// offsets[i+1] = incl[i] + bsum[block]; offsets[0] = 0
__global__ void scan3_kernel(const int* __restrict__ incl,
                             const int* __restrict__ bsum,
                             int* __restrict__ offsets)
{
    int i = blockIdx.x * 256 + threadIdx.x;
    if (i < N_NODES) offsets[i + 1] = incl[i] + bsum[blockIdx.x];
    if (i == 0) offsets[0] = 0;
}

// atomic-free scatter using precomputed rank
__global__ void scatter_kernel(const int* __restrict__ ei, int E,
                               const int* __restrict__ offsets,
                               const int* __restrict__ rank,
                               int* __restrict__ srcs)
{
    int e = blockIdx.x * blockDim.x + threadIdx.x;
    if (e >= E) return;
    int s = ei[e], d = ei[E + e];
    srcs[offsets[d] + rank[e]] = s;
}

// ---------------- layer 1 gather: one wave per dst node ---------------------
// Weight phase: lane l = (edge l>>3, head l&7) -> all 64 edge-head weights in
// parallel. Accumulate phase: lane l owns channels 2l,2l+1 (head l>>3), reads
// h rows as float2, one weight shuffle per edge, 8 edges fully unrolled.
__global__ void gather1_kernel(const float* __restrict__ h,
                               const float* __restrict__ ssrc,
                               const float* __restrict__ sdst,
                               const int* __restrict__ offsets,
                               const int* __restrict__ srcs,
                               const float* __restrict__ b1,
                               float* __restrict__ out)
{
    int d = (blockIdx.x * blockDim.x + threadIdx.x) >> 6;
    int lane = threadIdx.x & 63;
    if (d >= N_NODES) return;
    const int hw = lane & 7;            // head in weight phase
    const int hc = lane >> 3;           // head owning channels 2l, 2l+1
    const float sd_w = sdst[d * H1 + hw];

    float acc0 = 0.f, acc1 = 0.f;       // channels 2*lane, 2*lane+1
    float wsum = 0.f;                   // per (edge-slot, head hw) partials

    // self-loop (uses channel head hc directly)
    float ws_self;
    {
        float lg = ssrc[d * H1 + hc] + sdst[d * H1 + hc];
        lg = lg >= 0.f ? lg : NEG * lg;
        float w = __expf(lg);
        float2 v = ((const float2*)(h + (size_t)d * D1))[lane];
        acc0 = w * v.x; acc1 = w * v.y;
        ws_self = w;
    }

    const int beg = offsets[d], end = offsets[d + 1];
    int base = beg;
    for (; base + 8 <= end; base += 8) {
        int s_l = srcs[base + (lane >> 3)];
        float lg = ssrc[s_l * H1 + hw] + sd_w;
        lg = lg >= 0.f ? lg : NEG * lg;
        float w_l = __expf(lg);
        wsum += w_l;
#pragma unroll
        for (int j = 0; j < 8; ++j) {
            int s = __shfl(s_l, j << 3);
            float w = __shfl(w_l, (j << 3) | hc);
            float2 v = ((const float2*)(h + (size_t)s * D1))[lane];
            acc0 = fmaf(w, v.x, acc0);
            acc1 = fmaf(w, v.y, acc1);
        }
    }
    int cnt = end - base;
    if (cnt > 0) {
        int s_l = 0; float w_l = 0.f;
        if ((lane >> 3) < cnt) {
            s_l = srcs[base + (lane >> 3)];
            float lg = ssrc[s_l * H1 + hw] + sd_w;
            lg = lg >= 0.f ? lg : NEG * lg;
            w_l = __expf(lg);
        }
        wsum += w_l;
        for (int j = 0; j < cnt; ++j) {
            int s = __shfl(s_l, j << 3);
            float w = __shfl(w_l, (j << 3) | hc);
            float2 v = ((const float2*)(h + (size_t)s * D1))[lane];
            acc0 = fmaf(w, v.x, acc0);
            acc1 = fmaf(w, v.y, acc1);
        }
    }
    // head-wise total: sum wsum over the 8 edge-slot groups (xor bits 3..5)
    wsum += __shfl_xor(wsum, 8);
    wsum += __shfl_xor(wsum, 16);
    wsum += __shfl_xor(wsum, 32);
    // lane hc (0..7) now holds the edge-weight total for head hc
    float ws = ws_self + __shfl(wsum, hc);
    float inv = 1.f / (ws + 1e-16f);
    float2 bb = ((const float2*)b1)[lane];
    float v0 = acc0 * inv + bb.x;
    float v1 = acc1 * inv + bb.y;
    float2 r;
    r.x = v0 > 0.f ? v0 : 0.f;
    r.y = v1 > 0.f ? v1 : 0.f;
    ((float2*)(out + (size_t)d * D1))[lane] = r;
}

// ---------------- layer 2 GEMM: h2[N,40] = hrelu[N,128] @ W2[128,40] --------
__global__ void gemm2_kernel(const float* __restrict__ h,
                             const float* __restrict__ W2,
                             float* __restrict__ h2)
{
    int id = blockIdx.x * blockDim.x + threadIdx.x;
    if (id >= N_NODES * NCLS) return;
    int n = id / NCLS, c = id % NCLS;
    const float* hr = h + (size_t)n * D1;
    float acc = 0.f;
#pragma unroll 8
    for (int k = 0; k < D1; ++k)
        acc += hr[k] * W2[k * NCLS + c];
    h2[id] = acc;
}

// ---------------- per-node attention logits, layer 2 ------------------------
__global__ void logits2_kernel(const float* __restrict__ h2,
                               const float* __restrict__ a_src,
                               const float* __restrict__ a_dst,
                               float* __restrict__ ssrc,
                               float* __restrict__ sdst)
{
    int n = blockIdx.x * blockDim.x + threadIdx.x;
    if (n >= N_NODES) return;
    const float* hp = h2 + (size_t)n * NCLS;
    float as = 0.f, ad = 0.f;
#pragma unroll
    for (int c = 0; c < NCLS; ++c) {
        float v = hp[c];
        as += v * a_src[c];
        ad += v * a_dst[c];
    }
    ssrc[n] = as;
    sdst[n] = ad;
}

// ---------------- layer 2 gather + log_softmax: one wave per node -----------
// 64-edge chunks: lane l computes weight of edge base+l in parallel; rows
// streamed as float2 (lanes 0..19), 4-edge unroll for MLP.
__global__ void gather2_kernel(const float* __restrict__ h2,
                               const float* __restrict__ ssrc,
                               const float* __restrict__ sdst,
                               const int* __restrict__ offsets,
                               const int* __restrict__ srcs,
                               const float* __restrict__ b2,
                               float* __restrict__ out)
{
    int d = (blockIdx.x * blockDim.x + threadIdx.x) >> 6;
    int lane = threadIdx.x & 63;
    if (d >= N_NODES) return;
    const float sd = sdst[d];
    const bool act = lane < (NCLS / 2);   // 20 float2 lanes
    float acc0 = 0.f, acc1 = 0.f, ws = 0.f;

    // self-loop
    {
        float lg = ssrc[d] + sd; lg = lg >= 0.f ? lg : NEG * lg;
        float w = __expf(lg);
        float2 v = make_float2(0.f, 0.f);
        if (act) v = ((const float2*)(h2 + (size_t)d * NCLS))[lane];
        acc0 = w * v.x; acc1 = w * v.y;
        ws = w;
    }
    const int beg = offsets[d], end = offsets[d + 1];
    for (int base = beg; base < end; base += 64) {
        int cnt = end - base; if (cnt > 64) cnt = 64;
        int s_l = 0; float w_l = 0.f;
        if (lane < cnt) {
            s_l = srcs[base + lane];
            float lg = ssrc[s_l] + sd; lg = lg >= 0.f ? lg : NEG * lg;
            w_l = __expf(lg);
        }
        float t = w_l;
#pragma unroll
        for (int o = 32; o > 0; o >>= 1) t += __shfl_xor(t, o);
        ws += t;
        int j = 0;
        for (; j + 4 <= cnt; j += 4) {
            int s0 = __shfl(s_l, j),     s1 = __shfl(s_l, j + 1);
            int s2 = __shfl(s_l, j + 2), s3 = __shfl(s_l, j + 3);
            float w0 = __shfl(w_l, j),     w1 = __shfl(w_l, j + 1);
            float w2 = __shfl(w_l, j + 2), w3 = __shfl(w_l, j + 3);
            float2 v0 = make_float2(0.f, 0.f), v1 = v0, v2 = v0, v3 = v0;
            if (act) {
                v0 = ((const float2*)(h2 + (size_t)s0 * NCLS))[lane];
                v1 = ((const float2*)(h2 + (size_t)s1 * NCLS))[lane];
                v2 = ((const float2*)(h2 + (size_t)s2 * NCLS))[lane];
                v3 = ((const float2*)(h2 + (size_t)s3 * NCLS))[lane];
            }
            acc0 = fmaf(w0, v0.x, fmaf(w1, v1.x, fmaf(w2, v2.x, fmaf(w3, v3.x, acc0))));
            acc1 = fmaf(w0, v0.y, fmaf(w1, v1.y, fmaf(w2, v2.y, fmaf(w3, v3.y, acc1))));
        }
        for (; j < cnt; ++j) {
            int s0 = __shfl(s_l, j); float w0 = __shfl(w_l, j);
            float2 v0 = make_float2(0.f, 0.f);
            if (act) v0 = ((const float2*)(h2 + (size_t)s0 * NCLS))[lane];
            acc0 = fmaf(w0, v0.x, acc0);
            acc1 = fmaf(w0, v0.y, acc1);
        }
    }
    float l0 = -INFINITY, l1 = -INFINITY;
    if (act) {
        float inv = 1.f / (ws + 1e-16f);
        l0 = acc0 * inv + b2[2 * lane];
        l1 = acc1 * inv + b2[2 * lane + 1];
    }
    float m = fmaxf(l0, l1);
#pragma unroll
    for (int o = 32; o > 0; o >>= 1) m = fmaxf(m, __shfl_xor(m, o));
    float ex = act ? (__expf(l0 - m) + __expf(l1 - m)) : 0.f;
#pragma unroll
    for (int o = 32; o > 0; o >>= 1) ex += __shfl_xor(ex, o);
    float lse = __logf(ex) + m;
    if (act) {
        float2 r; r.x = l0 - lse; r.y = l1 - lse;
        ((float2*)(out + (size_t)d * NCLS))[lane] = r;
    }
}

extern "C" void kernel_launch(void* const* d_in, const int* in_sizes, int n_in,
                              void* d_out, int out_size, void* d_ws, size_t ws_size,
                              hipStream_t stream)
{
    const float* x   = (const float*)d_in[0];
    const int*   ei  = (const int*)  d_in[1];
    const float* W1  = (const float*)d_in[2];
    const float* as1 = (const float*)d_in[3];
    const float* ad1 = (const float*)d_in[4];
    const float* b1  = (const float*)d_in[5];
    const float* W2  = (const float*)d_in[6];
    const float* as2 = (const float*)d_in[7];
    const float* ad2 = (const float*)d_in[8];
    const float* b2  = (const float*)d_in[9];
    float* out = (float*)d_out;
    const int E = in_sizes[1] / 2;

    float* ws = (float*)d_ws;
    size_t off = 0;
    float* h1   = ws + off; off += (size_t)N_NODES * D1;
    float* h1r  = ws + off; off += (size_t)N_NODES * D1;
    float* ss1  = ws + off; off += (size_t)N_NODES * H1;
    float* sd1  = ws + off; off += (size_t)N_NODES * H1;
    float* h2   = ws + off; off += (size_t)N_NODES * NCLS;
    float* ss2  = ws + off; off += N_NODES;
    float* sd2  = ws + off; off += N_NODES;
    int* ib = (int*)(ws + off);
    size_t ioff = 0;
    int* deg     = ib + ioff; ioff += N_NODES;      // must be zeroed
    int* incl    = ib + ioff; ioff += N_NODES;
    int* offsets = ib + ioff; ioff += N_NODES + 1;
    int* bsum    = ib + ioff; ioff += 512;
    int* rank    = ib + ioff; ioff += E;
    int* srcs    = ib + ioff; ioff += E;

    hipMemsetAsync(deg, 0, (size_t)N_NODES * sizeof(int), stream);

    const int nb = (N_NODES + 255) / 256;           // 391
    // CSR build
    count_kernel<<<(E + 255) / 256, 256, 0, stream>>>(ei, E, deg, rank);
    scan1_kernel<<<nb, 256, 0, stream>>>(deg, incl, bsum);
    scan2_kernel<<<1, 512, 0, stream>>>(bsum, nb);
    scan3_kernel<<<nb, 256, 0, stream>>>(incl, bsum, offsets);
    scatter_kernel<<<(E + 255) / 256, 256, 0, stream>>>(ei, E, offsets, rank, srcs);

    // layer 1
    gemm1_kernel<<<N_NODES / 16, 256, 0, stream>>>(x, W1, h1);
    logits1_kernel<<<(N_NODES * H1 + 255) / 256, 256, 0, stream>>>(h1, as1, ad1, ss1, sd1);
    gather1_kernel<<<(N_NODES * 64 + 255) / 256, 256, 0, stream>>>(h1, ss1, sd1, offsets, srcs, b1, h1r);

    // layer 2
    gemm2_kernel<<<(N_NODES * NCLS + 255) / 256, 256, 0, stream>>>(h1r, W2, h2);
    logits2_kernel<<<(N_NODES + 255) / 256, 256, 0, stream>>>(h2, as2, ad2, ss2, sd2);
    gather2_kernel<<<(N_NODES * 64 + 255) / 256, 256, 0, stream>>>(h2, ss2, sd2, offsets, srcs, b2, out);
}

// Round 4
// 558.630 us; speedup vs baseline: 23.7638x; 1.1367x over previous
//
#include <hip/hip_runtime.h>
#include <math.h>

#define N_NODES 100000
#define F_IN    128
#define H1      8
#define C1      16
#define D1      128   // H1*C1
#define NCLS    40
#define NEG     0.2f

typedef unsigned int uint32;
typedef unsigned short ushort16;

__device__ __forceinline__ ushort16 f2bf(float f) {
    unsigned int u = __float_as_uint(f);
    u += 0x7fffu + ((u >> 16) & 1u);          // round-to-nearest-even
    return (ushort16)(u >> 16);
}
__device__ __forceinline__ float bf_lo(uint32 p) { return __uint_as_float(p << 16); }
__device__ __forceinline__ float bf_hi(uint32 p) { return __uint_as_float(p & 0xffff0000u); }

// ---------------- layer 1 GEMM: h1[N,128] = x[N,128] @ W1[128,128] (bf16 out)
__global__ void gemm1_kernel(const float* __restrict__ x,
                             const float* __restrict__ W,
                             ushort16* __restrict__ hb)
{
    __shared__ float xs[16][128];
    const int row0 = blockIdx.x * 16;
    const int t = threadIdx.x;
#pragma unroll
    for (int i = 0; i < 8; ++i) {
        int idx = t + i * 256;          // 0..2047
        int r = idx >> 7, c = idx & 127;
        xs[r][c] = x[(size_t)(row0 + r) * 128 + c];
    }
    __syncthreads();
    const int col = t & 127;
    const int half = t >> 7;            // 0 or 1; rows = half + 2*i
    float acc[8] = {0.f, 0.f, 0.f, 0.f, 0.f, 0.f, 0.f, 0.f};
    for (int k = 0; k < 128; ++k) {
        float w = W[k * 128 + col];
#pragma unroll
        for (int i = 0; i < 8; ++i)
            acc[i] += xs[half + 2 * i][k] * w;
    }
#pragma unroll
    for (int i = 0; i < 8; ++i)
        hb[(size_t)(row0 + half + 2 * i) * 128 + col] = f2bf(acc[i]);
}

// ---------------- per-node attention logits, layer 1 (bf16 h) ---------------
__global__ void logits1_kernel(const uint32* __restrict__ hb,   // N x 64 uints
                               const float* __restrict__ a_src,
                               const float* __restrict__ a_dst,
                               float* __restrict__ ssrc,
                               float* __restrict__ sdst)
{
    int id = blockIdx.x * blockDim.x + threadIdx.x;
    if (id >= N_NODES * H1) return;
    int n = id >> 3, hh = id & 7;
    const uint32* hp = hb + (size_t)n * 64 + hh * 8;
    float as = 0.f, ad = 0.f;
#pragma unroll
    for (int u = 0; u < 8; ++u) {
        uint32 p = hp[u];
        float v0 = bf_lo(p), v1 = bf_hi(p);
        as += v0 * a_src[hh * C1 + 2 * u] + v1 * a_src[hh * C1 + 2 * u + 1];
        ad += v0 * a_dst[hh * C1 + 2 * u] + v1 * a_dst[hh * C1 + 2 * u + 1];
    }
    ssrc[id] = as;
    sdst[id] = ad;
}

// ---------------- CSR build: histogram by dst, saving each edge's rank ------
__global__ void count_kernel(const int* __restrict__ ei, int E,
                             int* __restrict__ deg,
                             int* __restrict__ rank)
{
    int e = blockIdx.x * blockDim.x + threadIdx.x;
    if (e < E) rank[e] = atomicAdd(&deg[ei[E + e]], 1);
}

// block-local inclusive scan (256/block) + block sums
__global__ void scan1_kernel(const int* __restrict__ deg,
                             int* __restrict__ incl,
                             int* __restrict__ bsum)
{
    __shared__ int tmp[256];
    int i = blockIdx.x * 256 + threadIdx.x;
    int v = (i < N_NODES) ? deg[i] : 0;
    tmp[threadIdx.x] = v;
    __syncthreads();
    for (int o = 1; o < 256; o <<= 1) {
        int t = (threadIdx.x >= (unsigned)o) ? tmp[threadIdx.x - o] : 0;
        __syncthreads();
        tmp[threadIdx.x] += t;
        __syncthreads();
    }
    if (i < N_NODES) incl[i] = tmp[threadIdx.x];
    if (threadIdx.x == 255) bsum[blockIdx.x] = tmp[255];
}

// exclusive scan of block sums (nb <= 512), single block
__global__ void scan2_kernel(int* __restrict__ bsum, int nb)
{
    __shared__ int tmp[512];
    int v = (threadIdx.x < (unsigned)nb) ? bsum[threadIdx.x] : 0;
    tmp[threadIdx.x] = v;
    __syncthreads();
    for (int o = 1; o < 512; o <<= 1) {
        int t = (threadIdx.x >= (unsigned)o) ? tmp[threadIdx.x - o] : 0;
        __syncthreads();
        tmp[threadIdx.x] += t;
        __syncthreads();
    }
    if (threadIdx.x < (unsigned)nb) bsum[threadIdx.x] = tmp[threadIdx.x] - v;
}

// offsets[i+1] = incl[i] + bsum[block]; offsets[0] = 0
__global__ void scan3_kernel(const int* __restrict__ incl,
                             const int* __restrict__ bsum,
                             int* __restrict__ offsets)
{
    int i = blockIdx.x * 256 + threadIdx.x;
    if (i < N_NODES) offsets[i + 1] = incl[i] + bsum[blockIdx.x];
    if (i == 0) offsets[0] = 0;
}

// atomic-free scatter using precomputed rank
__global__ void scatter_kernel(const int* __restrict__ ei, int E,
                               const int* __restrict__ offsets,
                               const int* __restrict__ rank,
                               int* __restrict__ srcs)
{
    int e = blockIdx.x * blockDim.x + threadIdx.x;
    if (e >= E) return;
    int s = ei[e], d = ei[E + e];
    srcs[offsets[d] + rank[e]] = s;
}

// ---------------- layer 1 gather: one wave per dst node (bf16 h rows) -------
// Weight phase: lane l = (edge l>>3, head l&7). Accumulate phase: lane l owns
// channels 2l,2l+1 (head l>>3); row read = 64 dword lanes = 256 B bf16 row.
__global__ void gather1_kernel(const uint32* __restrict__ hb,   // N x 64 uints
                               const float* __restrict__ ssrc,
                               const float* __restrict__ sdst,
                               const int* __restrict__ offsets,
                               const int* __restrict__ srcs,
                               const float* __restrict__ b1,
                               float* __restrict__ out)
{
    int d = (blockIdx.x * blockDim.x + threadIdx.x) >> 6;
    int lane = threadIdx.x & 63;
    if (d >= N_NODES) return;
    const int hw = lane & 7;            // head in weight phase
    const int hc = lane >> 3;           // head owning channels 2l, 2l+1
    const float sd_w = sdst[d * H1 + hw];

    float acc0 = 0.f, acc1 = 0.f;
    float wsum = 0.f;

    // self-loop
    float ws_self;
    {
        float lg = ssrc[d * H1 + hc] + sdst[d * H1 + hc];
        lg = lg >= 0.f ? lg : NEG * lg;
        float w = __expf(lg);
        uint32 p = hb[(size_t)d * 64 + lane];
        acc0 = w * bf_lo(p); acc1 = w * bf_hi(p);
        ws_self = w;
    }

    const int beg = offsets[d], end = offsets[d + 1];
    int base = beg;
    for (; base + 8 <= end; base += 8) {
        int s_l = srcs[base + (lane >> 3)];
        float lg = ssrc[s_l * H1 + hw] + sd_w;
        lg = lg >= 0.f ? lg : NEG * lg;
        float w_l = __expf(lg);
        wsum += w_l;
#pragma unroll
        for (int j = 0; j < 8; ++j) {
            int s = __shfl(s_l, j << 3);
            float w = __shfl(w_l, (j << 3) | hc);
            uint32 p = hb[(size_t)s * 64 + lane];
            acc0 = fmaf(w, bf_lo(p), acc0);
            acc1 = fmaf(w, bf_hi(p), acc1);
        }
    }
    int cnt = end - base;
    if (cnt > 0) {
        int s_l = 0; float w_l = 0.f;
        if ((lane >> 3) < cnt) {
            s_l = srcs[base + (lane >> 3)];
            float lg = ssrc[s_l * H1 + hw] + sd_w;
            lg = lg >= 0.f ? lg : NEG * lg;
            w_l = __expf(lg);
        }
        wsum += w_l;
        for (int j = 0; j < cnt; ++j) {
            int s = __shfl(s_l, j << 3);
            float w = __shfl(w_l, (j << 3) | hc);
            uint32 p = hb[(size_t)s * 64 + lane];
            acc0 = fmaf(w, bf_lo(p), acc0);
            acc1 = fmaf(w, bf_hi(p), acc1);
        }
    }
    // head-wise total: sum wsum over the 8 edge-slot groups (xor bits 3..5)
    wsum += __shfl_xor(wsum, 8);
    wsum += __shfl_xor(wsum, 16);
    wsum += __shfl_xor(wsum, 32);
    float ws = ws_self + __shfl(wsum, hc);
    float inv = 1.f / (ws + 1e-16f);
    float2 bb = ((const float2*)b1)[lane];
    float v0 = acc0 * inv + bb.x;
    float v1 = acc1 * inv + bb.y;
    float2 r;
    r.x = v0 > 0.f ? v0 : 0.f;
    r.y = v1 > 0.f ? v1 : 0.f;
    ((float2*)(out + (size_t)d * D1))[lane] = r;
}

// ---------------- layer 2 GEMM: h2[N,40] = hrelu[N,128] @ W2[128,40] (bf16) -
__global__ void gemm2_kernel(const float* __restrict__ h,
                             const float* __restrict__ W2,
                             ushort16* __restrict__ h2b)
{
    int id = blockIdx.x * blockDim.x + threadIdx.x;
    if (id >= N_NODES * NCLS) return;
    int n = id / NCLS, c = id % NCLS;
    const float* hr = h + (size_t)n * D1;
    float acc = 0.f;
#pragma unroll 8
    for (int k = 0; k < D1; ++k)
        acc += hr[k] * W2[k * NCLS + c];
    h2b[id] = f2bf(acc);
}

// ---------------- per-node attention logits, layer 2 (bf16 h2) --------------
__global__ void logits2_kernel(const uint32* __restrict__ h2b,  // N x 20 uints
                               const float* __restrict__ a_src,
                               const float* __restrict__ a_dst,
                               float* __restrict__ ssrc,
                               float* __restrict__ sdst)
{
    int n = blockIdx.x * blockDim.x + threadIdx.x;
    if (n >= N_NODES) return;
    const uint32* hp = h2b + (size_t)n * 20;
    float as = 0.f, ad = 0.f;
#pragma unroll
    for (int u = 0; u < 20; ++u) {
        uint32 p = hp[u];
        float v0 = bf_lo(p), v1 = bf_hi(p);
        as += v0 * a_src[2 * u] + v1 * a_src[2 * u + 1];
        ad += v0 * a_dst[2 * u] + v1 * a_dst[2 * u + 1];
    }
    ssrc[n] = as;
    sdst[n] = ad;
}

// ---------------- layer 2 gather + log_softmax: one wave per node (bf16) ----
__global__ void gather2_kernel(const uint32* __restrict__ h2b,  // N x 20 uints
                               const float* __restrict__ ssrc,
                               const float* __restrict__ sdst,
                               const int* __restrict__ offsets,
                               const int* __restrict__ srcs,
                               const float* __restrict__ b2,
                               float* __restrict__ out)
{
    int d = (blockIdx.x * blockDim.x + threadIdx.x) >> 6;
    int lane = threadIdx.x & 63;
    if (d >= N_NODES) return;
    const float sd = sdst[d];
    const bool act = lane < (NCLS / 2);   // 20 dword lanes
    float acc0 = 0.f, acc1 = 0.f, ws = 0.f;

    // self-loop
    {
        float lg = ssrc[d] + sd; lg = lg >= 0.f ? lg : NEG * lg;
        float w = __expf(lg);
        uint32 p = act ? h2b[(size_t)d * 20 + lane] : 0u;
        acc0 = w * bf_lo(p); acc1 = w * bf_hi(p);
        ws = w;
    }
    const int beg = offsets[d], end = offsets[d + 1];
    for (int base = beg; base < end; base += 64) {
        int cnt = end - base; if (cnt > 64) cnt = 64;
        int s_l = 0; float w_l = 0.f;
        if (lane < cnt) {
            s_l = srcs[base + lane];
            float lg = ssrc[s_l] + sd; lg = lg >= 0.f ? lg : NEG * lg;
            w_l = __expf(lg);
        }
        float t = w_l;
#pragma unroll
        for (int o = 32; o > 0; o >>= 1) t += __shfl_xor(t, o);
        ws += t;
        int j = 0;
        for (; j + 4 <= cnt; j += 4) {
            int s0 = __shfl(s_l, j),     s1 = __shfl(s_l, j + 1);
            int s2 = __shfl(s_l, j + 2), s3 = __shfl(s_l, j + 3);
            float w0 = __shfl(w_l, j),     w1 = __shfl(w_l, j + 1);
            float w2 = __shfl(w_l, j + 2), w3 = __shfl(w_l, j + 3);
            uint32 p0 = 0u, p1 = 0u, p2 = 0u, p3 = 0u;
            if (act) {
                p0 = h2b[(size_t)s0 * 20 + lane];
                p1 = h2b[(size_t)s1 * 20 + lane];
                p2 = h2b[(size_t)s2 * 20 + lane];
                p3 = h2b[(size_t)s3 * 20 + lane];
            }
            acc0 = fmaf(w0, bf_lo(p0), fmaf(w1, bf_lo(p1), fmaf(w2, bf_lo(p2), fmaf(w3, bf_lo(p3), acc0))));
            acc1 = fmaf(w0, bf_hi(p0), fmaf(w1, bf_hi(p1), fmaf(w2, bf_hi(p2), fmaf(w3, bf_hi(p3), acc1))));
        }
        for (; j < cnt; ++j) {
            int s0 = __shfl(s_l, j); float w0 = __shfl(w_l, j);
            uint32 p0 = act ? h2b[(size_t)s0 * 20 + lane] : 0u;
            acc0 = fmaf(w0, bf_lo(p0), acc0);
            acc1 = fmaf(w0, bf_hi(p0), acc1);
        }
    }
    float l0 = -INFINITY, l1 = -INFINITY;
    if (act) {
        float inv = 1.f / (ws + 1e-16f);
        l0 = acc0 * inv + b2[2 * lane];
        l1 = acc1 * inv + b2[2 * lane + 1];
    }
    float m = fmaxf(l0, l1);
#pragma unroll
    for (int o = 32; o > 0; o >>= 1) m = fmaxf(m, __shfl_xor(m, o));
    float ex = act ? (__expf(l0 - m) + __expf(l1 - m)) : 0.f;
#pragma unroll
    for (int o = 32; o > 0; o >>= 1) ex += __shfl_xor(ex, o);
    float lse = __logf(ex) + m;
    if (act) {
        float2 r; r.x = l0 - lse; r.y = l1 - lse;
        ((float2*)(out + (size_t)d * NCLS))[lane] = r;
    }
}

extern "C" void kernel_launch(void* const* d_in, const int* in_sizes, int n_in,
                              void* d_out, int out_size, void* d_ws, size_t ws_size,
                              hipStream_t stream)
{
    const float* x   = (const float*)d_in[0];
    const int*   ei  = (const int*)  d_in[1];
    const float* W1  = (const float*)d_in[2];
    const float* as1 = (const float*)d_in[3];
    const float* ad1 = (const float*)d_in[4];
    const float* b1  = (const float*)d_in[5];
    const float* W2  = (const float*)d_in[6];
    const float* as2 = (const float*)d_in[7];
    const float* ad2 = (const float*)d_in[8];
    const float* b2  = (const float*)d_in[9];
    float* out = (float*)d_out;
    const int E = in_sizes[1] / 2;

    float* ws = (float*)d_ws;
    size_t off = 0;
    uint32* h1b = (uint32*)(ws + off); off += (size_t)N_NODES * 64;   // bf16 N x 128
    float* h1r  = ws + off; off += (size_t)N_NODES * D1;
    float* ss1  = ws + off; off += (size_t)N_NODES * H1;
    float* sd1  = ws + off; off += (size_t)N_NODES * H1;
    uint32* h2b = (uint32*)(ws + off); off += (size_t)N_NODES * 20;   // bf16 N x 40
    float* ss2  = ws + off; off += N_NODES;
    float* sd2  = ws + off; off += N_NODES;
    int* ib = (int*)(ws + off);
    size_t ioff = 0;
    int* deg     = ib + ioff; ioff += N_NODES;      // must be zeroed
    int* incl    = ib + ioff; ioff += N_NODES;
    int* offsets = ib + ioff; ioff += N_NODES + 1;
    int* bsum    = ib + ioff; ioff += 512;
    int* rank    = ib + ioff; ioff += E;
    int* srcs    = ib + ioff; ioff += E;

    hipMemsetAsync(deg, 0, (size_t)N_NODES * sizeof(int), stream);

    const int nb = (N_NODES + 255) / 256;           // 391
    // CSR build
    count_kernel<<<(E + 255) / 256, 256, 0, stream>>>(ei, E, deg, rank);
    scan1_kernel<<<nb, 256, 0, stream>>>(deg, incl, bsum);
    scan2_kernel<<<1, 512, 0, stream>>>(bsum, nb);
    scan3_kernel<<<nb, 256, 0, stream>>>(incl, bsum, offsets);
    scatter_kernel<<<(E + 255) / 256, 256, 0, stream>>>(ei, E, offsets, rank, srcs);

    // layer 1
    gemm1_kernel<<<N_NODES / 16, 256, 0, stream>>>(x, W1, (ushort16*)h1b);
    logits1_kernel<<<(N_NODES * H1 + 255) / 256, 256, 0, stream>>>(h1b, as1, ad1, ss1, sd1);
    gather1_kernel<<<(N_NODES * 64 + 255) / 256, 256, 0, stream>>>(h1b, ss1, sd1, offsets, srcs, b1, h1r);

    // layer 2
    gemm2_kernel<<<(N_NODES * NCLS + 255) / 256, 256, 0, stream>>>(h1r, W2, (ushort16*)h2b);
    logits2_kernel<<<(N_NODES + 255) / 256, 256, 0, stream>>>(h2b, as2, ad2, ss2, sd2);
    gather2_kernel<<<(N_NODES * 64 + 255) / 256, 256, 0, stream>>>(h2b, ss2, sd2, offsets, srcs, b2, out);
}

// Round 5
// 466.411 us; speedup vs baseline: 28.4624x; 1.1977x over previous
//
#include <hip/hip_runtime.h>
#include <math.h>

#define N_NODES 100000
#define F_IN    128
#define H1      8
#define C1      16
#define D1      128   // H1*C1
#define NCLS    40
#define NEG     0.2f

typedef unsigned int uint32;
typedef unsigned short ushort16;

__device__ __forceinline__ ushort16 f2bf(float f) {
    unsigned int u = __float_as_uint(f);
    u += 0x7fffu + ((u >> 16) & 1u);          // round-to-nearest-even
    return (ushort16)(u >> 16);
}
__device__ __forceinline__ float bf_lo(uint32 p) { return __uint_as_float(p << 16); }
__device__ __forceinline__ float bf_hi(uint32 p) { return __uint_as_float(p & 0xffff0000u); }

// ---------------- layer 1 GEMM + logits, fused ------------------------------
// 64 rows/block; thread = 4 rows x 8 cols; x tile staged in LDS (132 pad).
// Epilogue: bf16 h1 (packed uint4 stores) + per-(row,head) attention logits
// computed from the fp32 tile written back into LDS.
__global__ __launch_bounds__(256) void gemm1_kernel(
    const float* __restrict__ x, const float* __restrict__ W,
    uint32* __restrict__ hb,            // bf16 packed pairs, N x 64 uints
    const float* __restrict__ a_src, const float* __restrict__ a_dst,
    float* __restrict__ ssrc, float* __restrict__ sdst)
{
    __shared__ float xs[64][132];
    const int row0 = blockIdx.x * 64;
    const int tid = threadIdx.x;
#pragma unroll
    for (int i = 0; i < 8; ++i) {
        int idx = tid + i * 256;      // 0..2047
        int r = idx >> 5, c4 = idx & 31;
        float4 v = make_float4(0.f, 0.f, 0.f, 0.f);
        if (row0 + r < N_NODES)
            v = ((const float4*)x)[(size_t)(row0 + r) * 32 + c4];
        *(float4*)&xs[r][c4 * 4] = v;
    }
    __syncthreads();
    const int cg = tid & 15;          // cols 8cg..8cg+7
    const int rg = tid >> 4;          // rows rg+16i, i=0..3
    float acc[4][8];
#pragma unroll
    for (int i = 0; i < 4; ++i)
#pragma unroll
        for (int j = 0; j < 8; ++j) acc[i][j] = 0.f;

    for (int k0 = 0; k0 < 128; k0 += 4) {
        float4 wa[4], wb[4];
#pragma unroll
        for (int kk = 0; kk < 4; ++kk) {
            wa[kk] = ((const float4*)W)[(k0 + kk) * 32 + 2 * cg];
            wb[kk] = ((const float4*)W)[(k0 + kk) * 32 + 2 * cg + 1];
        }
#pragma unroll
        for (int i = 0; i < 4; ++i) {
            float4 hx = *(const float4*)&xs[rg + 16 * i][k0];
            float hv[4] = {hx.x, hx.y, hx.z, hx.w};
#pragma unroll
            for (int kk = 0; kk < 4; ++kk) {
                acc[i][0] = fmaf(hv[kk], wa[kk].x, acc[i][0]);
                acc[i][1] = fmaf(hv[kk], wa[kk].y, acc[i][1]);
                acc[i][2] = fmaf(hv[kk], wa[kk].z, acc[i][2]);
                acc[i][3] = fmaf(hv[kk], wa[kk].w, acc[i][3]);
                acc[i][4] = fmaf(hv[kk], wb[kk].x, acc[i][4]);
                acc[i][5] = fmaf(hv[kk], wb[kk].y, acc[i][5]);
                acc[i][6] = fmaf(hv[kk], wb[kk].z, acc[i][6]);
                acc[i][7] = fmaf(hv[kk], wb[kk].w, acc[i][7]);
            }
        }
    }
    __syncthreads();   // all reads of x tile done
#pragma unroll
    for (int i = 0; i < 4; ++i) {
        int r = rg + 16 * i;
        uint4 pk;
        pk.x = ((uint32)f2bf(acc[i][0])) | ((uint32)f2bf(acc[i][1]) << 16);
        pk.y = ((uint32)f2bf(acc[i][2])) | ((uint32)f2bf(acc[i][3]) << 16);
        pk.z = ((uint32)f2bf(acc[i][4])) | ((uint32)f2bf(acc[i][5]) << 16);
        pk.w = ((uint32)f2bf(acc[i][6])) | ((uint32)f2bf(acc[i][7]) << 16);
        if (row0 + r < N_NODES)
            ((uint4*)hb)[(size_t)(row0 + r) * 16 + cg] = pk;
        *(float4*)&xs[r][8 * cg]     = make_float4(acc[i][0], acc[i][1], acc[i][2], acc[i][3]);
        *(float4*)&xs[r][8 * cg + 4] = make_float4(acc[i][4], acc[i][5], acc[i][6], acc[i][7]);
    }
    __syncthreads();
    // logits: 64 rows x 8 heads = 512 tasks, 2 per thread
#pragma unroll
    for (int t = 0; t < 2; ++t) {
        int task = tid + t * 256;
        int r = task >> 3, hh = task & 7;
        if (row0 + r < N_NODES) {
            float as = 0.f, ad = 0.f;
#pragma unroll
            for (int c = 0; c < 16; ++c) {
                float v = xs[r][hh * 16 + c];
                as = fmaf(v, a_src[hh * 16 + c], as);
                ad = fmaf(v, a_dst[hh * 16 + c], ad);
            }
            ssrc[(row0 + r) * 8 + hh] = as;
            sdst[(row0 + r) * 8 + hh] = ad;
        }
    }
}

// ---------------- CSR build: histogram by dst, saving each edge's rank ------
__global__ void count_kernel(const int* __restrict__ ei, int E,
                             int* __restrict__ deg,
                             int* __restrict__ rank)
{
    int e = blockIdx.x * blockDim.x + threadIdx.x;
    if (e < E) rank[e] = atomicAdd(&deg[ei[E + e]], 1);
}

// block-local inclusive scan (256/block) + block sums
__global__ void scan1_kernel(const int* __restrict__ deg,
                             int* __restrict__ incl,
                             int* __restrict__ bsum)
{
    __shared__ int tmp[256];
    int i = blockIdx.x * 256 + threadIdx.x;
    int v = (i < N_NODES) ? deg[i] : 0;
    tmp[threadIdx.x] = v;
    __syncthreads();
    for (int o = 1; o < 256; o <<= 1) {
        int t = (threadIdx.x >= (unsigned)o) ? tmp[threadIdx.x - o] : 0;
        __syncthreads();
        tmp[threadIdx.x] += t;
        __syncthreads();
    }
    if (i < N_NODES) incl[i] = tmp[threadIdx.x];
    if (threadIdx.x == 255) bsum[blockIdx.x] = tmp[255];
}

// exclusive scan of block sums (nb <= 512), single block
__global__ void scan2_kernel(int* __restrict__ bsum, int nb)
{
    __shared__ int tmp[512];
    int v = (threadIdx.x < (unsigned)nb) ? bsum[threadIdx.x] : 0;
    tmp[threadIdx.x] = v;
    __syncthreads();
    for (int o = 1; o < 512; o <<= 1) {
        int t = (threadIdx.x >= (unsigned)o) ? tmp[threadIdx.x - o] : 0;
        __syncthreads();
        tmp[threadIdx.x] += t;
        __syncthreads();
    }
    if (threadIdx.x < (unsigned)nb) bsum[threadIdx.x] = tmp[threadIdx.x] - v;
}

// offsets[i+1] = incl[i] + bsum[block]; offsets[0] = 0
__global__ void scan3_kernel(const int* __restrict__ incl,
                             const int* __restrict__ bsum,
                             int* __restrict__ offsets)
{
    int i = blockIdx.x * 256 + threadIdx.x;
    if (i < N_NODES) offsets[i + 1] = incl[i] + bsum[blockIdx.x];
    if (i == 0) offsets[0] = 0;
}

// atomic-free scatter using precomputed rank
__global__ void scatter_kernel(const int* __restrict__ ei, int E,
                               const int* __restrict__ offsets,
                               const int* __restrict__ rank,
                               int* __restrict__ srcs)
{
    int e = blockIdx.x * blockDim.x + threadIdx.x;
    if (e >= E) return;
    int s = ei[e], d = ei[E + e];
    srcs[offsets[d] + rank[e]] = s;
}

// ---------------- layer 1 gather: one wave per dst node (bf16 h rows) -------
__global__ void gather1_kernel(const uint32* __restrict__ hb,   // N x 64 uints
                               const float* __restrict__ ssrc,
                               const float* __restrict__ sdst,
                               const int* __restrict__ offsets,
                               const int* __restrict__ srcs,
                               const float* __restrict__ b1,
                               float* __restrict__ out)
{
    int d = (blockIdx.x * blockDim.x + threadIdx.x) >> 6;
    int lane = threadIdx.x & 63;
    if (d >= N_NODES) return;
    const int hw = lane & 7;            // head in weight phase
    const int hc = lane >> 3;           // head owning channels 2l, 2l+1
    const float sd_w = sdst[d * H1 + hw];

    float acc0 = 0.f, acc1 = 0.f;
    float wsum = 0.f;

    // self-loop
    float ws_self;
    {
        float lg = ssrc[d * H1 + hc] + sdst[d * H1 + hc];
        lg = lg >= 0.f ? lg : NEG * lg;
        float w = __expf(lg);
        uint32 p = hb[(size_t)d * 64 + lane];
        acc0 = w * bf_lo(p); acc1 = w * bf_hi(p);
        ws_self = w;
    }

    const int beg = offsets[d], end = offsets[d + 1];
    int base = beg;
    for (; base + 8 <= end; base += 8) {
        int s_l = srcs[base + (lane >> 3)];
        float lg = ssrc[s_l * H1 + hw] + sd_w;
        lg = lg >= 0.f ? lg : NEG * lg;
        float w_l = __expf(lg);
        wsum += w_l;
#pragma unroll
        for (int j = 0; j < 8; ++j) {
            int s = __shfl(s_l, j << 3);
            float w = __shfl(w_l, (j << 3) | hc);
            uint32 p = hb[(size_t)s * 64 + lane];
            acc0 = fmaf(w, bf_lo(p), acc0);
            acc1 = fmaf(w, bf_hi(p), acc1);
        }
    }
    int cnt = end - base;
    if (cnt > 0) {
        int s_l = 0; float w_l = 0.f;
        if ((lane >> 3) < cnt) {
            s_l = srcs[base + (lane >> 3)];
            float lg = ssrc[s_l * H1 + hw] + sd_w;
            lg = lg >= 0.f ? lg : NEG * lg;
            w_l = __expf(lg);
        }
        wsum += w_l;
        for (int j = 0; j < cnt; ++j) {
            int s = __shfl(s_l, j << 3);
            float w = __shfl(w_l, (j << 3) | hc);
            uint32 p = hb[(size_t)s * 64 + lane];
            acc0 = fmaf(w, bf_lo(p), acc0);
            acc1 = fmaf(w, bf_hi(p), acc1);
        }
    }
    // head-wise total: sum wsum over the 8 edge-slot groups (xor bits 3..5)
    wsum += __shfl_xor(wsum, 8);
    wsum += __shfl_xor(wsum, 16);
    wsum += __shfl_xor(wsum, 32);
    float ws = ws_self + __shfl(wsum, hc);
    float inv = 1.f / (ws + 1e-16f);
    float2 bb = ((const float2*)b1)[lane];
    float v0 = acc0 * inv + bb.x;
    float v1 = acc1 * inv + bb.y;
    float2 r;
    r.x = v0 > 0.f ? v0 : 0.f;
    r.y = v1 > 0.f ? v1 : 0.f;
    ((float2*)(out + (size_t)d * D1))[lane] = r;
}

// ---------------- layer 2 GEMM + logits, fused ------------------------------
// 32 rows/block (exact: 3125 blocks); W2 transposed in LDS (40x132),
// h rows in LDS (32x132); thread = (row, 5-col group). Epilogue computes
// ss2/sd2 from the fp32 row written back into LDS.
__global__ __launch_bounds__(256) void gemm2_kernel(
    const float* __restrict__ h, const float* __restrict__ W2,
    ushort16* __restrict__ h2b,
    const float* __restrict__ a_src, const float* __restrict__ a_dst,
    float* __restrict__ ssrc, float* __restrict__ sdst)
{
    __shared__ float w2s[40][132];
    __shared__ float hs[32][132];
    const int row0 = blockIdx.x * 32;
    const int tid = threadIdx.x;
#pragma unroll
    for (int i = 0; i < 20; ++i) {
        int idx = tid + i * 256;     // 0..5119
        int k = idx / 40, c = idx % 40;
        w2s[c][k] = W2[idx];
    }
#pragma unroll
    for (int i = 0; i < 4; ++i) {
        int idx = tid + i * 256;     // 0..1023
        int r = idx >> 5, c4 = idx & 31;
        *(float4*)&hs[r][c4 * 4] = ((const float4*)h)[(size_t)(row0 + r) * 32 + c4];
    }
    __syncthreads();
    const int rg = tid >> 3;     // row 0..31
    const int g  = tid & 7;      // cols 5g..5g+4
    float acc[5] = {0.f, 0.f, 0.f, 0.f, 0.f};
    for (int k0 = 0; k0 < 128; k0 += 4) {
        float4 hv = *(const float4*)&hs[rg][k0];
#pragma unroll
        for (int j = 0; j < 5; ++j) {
            float4 wv = *(const float4*)&w2s[5 * g + j][k0];
            acc[j] = fmaf(hv.x, wv.x, acc[j]);
            acc[j] = fmaf(hv.y, wv.y, acc[j]);
            acc[j] = fmaf(hv.z, wv.z, acc[j]);
            acc[j] = fmaf(hv.w, wv.w, acc[j]);
        }
    }
#pragma unroll
    for (int j = 0; j < 5; ++j)
        h2b[(size_t)(row0 + rg) * 40 + 5 * g + j] = f2bf(acc[j]);
    __syncthreads();     // all reads of hs done
#pragma unroll
    for (int j = 0; j < 5; ++j)
        hs[rg][5 * g + j] = acc[j];
    __syncthreads();
    if (tid < 32) {
        float as = 0.f, ad = 0.f;
#pragma unroll
        for (int c = 0; c < 40; ++c) {
            float v = hs[tid][c];
            as = fmaf(v, a_src[c], as);
            ad = fmaf(v, a_dst[c], ad);
        }
        ssrc[row0 + tid] = as;
        sdst[row0 + tid] = ad;
    }
}

// ---------------- layer 2 gather + log_softmax: one wave per node (bf16) ----
__global__ void gather2_kernel(const uint32* __restrict__ h2b,  // N x 20 uints
                               const float* __restrict__ ssrc,
                               const float* __restrict__ sdst,
                               const int* __restrict__ offsets,
                               const int* __restrict__ srcs,
                               const float* __restrict__ b2,
                               float* __restrict__ out)
{
    int d = (blockIdx.x * blockDim.x + threadIdx.x) >> 6;
    int lane = threadIdx.x & 63;
    if (d >= N_NODES) return;
    const float sd = sdst[d];
    const bool act = lane < (NCLS / 2);   // 20 dword lanes
    float acc0 = 0.f, acc1 = 0.f, ws = 0.f;

    // self-loop
    {
        float lg = ssrc[d] + sd; lg = lg >= 0.f ? lg : NEG * lg;
        float w = __expf(lg);
        uint32 p = act ? h2b[(size_t)d * 20 + lane] : 0u;
        acc0 = w * bf_lo(p); acc1 = w * bf_hi(p);
        ws = w;
    }
    const int beg = offsets[d], end = offsets[d + 1];
    for (int base = beg; base < end; base += 64) {
        int cnt = end - base; if (cnt > 64) cnt = 64;
        int s_l = 0; float w_l = 0.f;
        if (lane < cnt) {
            s_l = srcs[base + lane];
            float lg = ssrc[s_l] + sd; lg = lg >= 0.f ? lg : NEG * lg;
            w_l = __expf(lg);
        }
        float t = w_l;
#pragma unroll
        for (int o = 32; o > 0; o >>= 1) t += __shfl_xor(t, o);
        ws += t;
        int j = 0;
        for (; j + 4 <= cnt; j += 4) {
            int s0 = __shfl(s_l, j),     s1 = __shfl(s_l, j + 1);
            int s2 = __shfl(s_l, j + 2), s3 = __shfl(s_l, j + 3);
            float w0 = __shfl(w_l, j),     w1 = __shfl(w_l, j + 1);
            float w2 = __shfl(w_l, j + 2), w3 = __shfl(w_l, j + 3);
            uint32 p0 = 0u, p1 = 0u, p2 = 0u, p3 = 0u;
            if (act) {
                p0 = h2b[(size_t)s0 * 20 + lane];
                p1 = h2b[(size_t)s1 * 20 + lane];
                p2 = h2b[(size_t)s2 * 20 + lane];
                p3 = h2b[(size_t)s3 * 20 + lane];
            }
            acc0 = fmaf(w0, bf_lo(p0), fmaf(w1, bf_lo(p1), fmaf(w2, bf_lo(p2), fmaf(w3, bf_lo(p3), acc0))));
            acc1 = fmaf(w0, bf_hi(p0), fmaf(w1, bf_hi(p1), fmaf(w2, bf_hi(p2), fmaf(w3, bf_hi(p3), acc1))));
        }
        for (; j < cnt; ++j) {
            int s0 = __shfl(s_l, j); float w0 = __shfl(w_l, j);
            uint32 p0 = act ? h2b[(size_t)s0 * 20 + lane] : 0u;
            acc0 = fmaf(w0, bf_lo(p0), acc0);
            acc1 = fmaf(w0, bf_hi(p0), acc1);
        }
    }
    float l0 = -INFINITY, l1 = -INFINITY;
    if (act) {
        float inv = 1.f / (ws + 1e-16f);
        l0 = acc0 * inv + b2[2 * lane];
        l1 = acc1 * inv + b2[2 * lane + 1];
    }
    float m = fmaxf(l0, l1);
#pragma unroll
    for (int o = 32; o > 0; o >>= 1) m = fmaxf(m, __shfl_xor(m, o));
    float ex = act ? (__expf(l0 - m) + __expf(l1 - m)) : 0.f;
#pragma unroll
    for (int o = 32; o > 0; o >>= 1) ex += __shfl_xor(ex, o);
    float lse = __logf(ex) + m;
    if (act) {
        float2 r; r.x = l0 - lse; r.y = l1 - lse;
        ((float2*)(out + (size_t)d * NCLS))[lane] = r;
    }
}

extern "C" void kernel_launch(void* const* d_in, const int* in_sizes, int n_in,
                              void* d_out, int out_size, void* d_ws, size_t ws_size,
                              hipStream_t stream)
{
    const float* x   = (const float*)d_in[0];
    const int*   ei  = (const int*)  d_in[1];
    const float* W1  = (const float*)d_in[2];
    const float* as1 = (const float*)d_in[3];
    const float* ad1 = (const float*)d_in[4];
    const float* b1  = (const float*)d_in[5];
    const float* W2  = (const float*)d_in[6];
    const float* as2 = (const float*)d_in[7];
    const float* ad2 = (const float*)d_in[8];
    const float* b2  = (const float*)d_in[9];
    float* out = (float*)d_out;
    const int E = in_sizes[1] / 2;

    float* ws = (float*)d_ws;
    size_t off = 0;
    uint32* h1b = (uint32*)(ws + off); off += (size_t)N_NODES * 64;   // bf16 N x 128
    float* h1r  = ws + off; off += (size_t)N_NODES * D1;
    float* ss1  = ws + off; off += (size_t)N_NODES * H1;
    float* sd1  = ws + off; off += (size_t)N_NODES * H1;
    uint32* h2b = (uint32*)(ws + off); off += (size_t)N_NODES * 20;   // bf16 N x 40
    float* ss2  = ws + off; off += N_NODES;
    float* sd2  = ws + off; off += N_NODES;
    int* ib = (int*)(ws + off);
    size_t ioff = 0;
    int* deg     = ib + ioff; ioff += N_NODES;      // must be zeroed
    int* incl    = ib + ioff; ioff += N_NODES;
    int* offsets = ib + ioff; ioff += N_NODES + 1;
    int* bsum    = ib + ioff; ioff += 512;
    int* rank    = ib + ioff; ioff += E;
    int* srcs    = ib + ioff; ioff += E;

    hipMemsetAsync(deg, 0, (size_t)N_NODES * sizeof(int), stream);

    const int nb = (N_NODES + 255) / 256;           // 391
    // CSR build
    count_kernel<<<(E + 255) / 256, 256, 0, stream>>>(ei, E, deg, rank);
    scan1_kernel<<<nb, 256, 0, stream>>>(deg, incl, bsum);
    scan2_kernel<<<1, 512, 0, stream>>>(bsum, nb);
    scan3_kernel<<<nb, 256, 0, stream>>>(incl, bsum, offsets);
    scatter_kernel<<<(E + 255) / 256, 256, 0, stream>>>(ei, E, offsets, rank, srcs);

    // layer 1 (gemm + logits fused)
    gemm1_kernel<<<(N_NODES + 63) / 64, 256, 0, stream>>>(x, W1, h1b, as1, ad1, ss1, sd1);
    gather1_kernel<<<(N_NODES * 64 + 255) / 256, 256, 0, stream>>>(h1b, ss1, sd1, offsets, srcs, b1, h1r);

    // layer 2 (gemm + logits fused)
    gemm2_kernel<<<N_NODES / 32, 256, 0, stream>>>(h1r, W2, (ushort16*)h2b, as2, ad2, ss2, sd2);
    gather2_kernel<<<(N_NODES * 64 + 255) / 256, 256, 0, stream>>>(h2b, ss2, sd2, offsets, srcs, b2, out);
}

// Round 6
// 424.231 us; speedup vs baseline: 31.2924x; 1.0994x over previous
//
#include <hip/hip_runtime.h>
#include <math.h>

#define N_NODES 100000
#define F_IN    128
#define H1      8
#define C1      16
#define D1      128   // H1*C1
#define NCLS    40
#define NEG     0.2f

typedef unsigned int uint32;
typedef unsigned short ushort16;
typedef float v2f __attribute__((ext_vector_type(2)));

__device__ __forceinline__ ushort16 f2bf(float f) {
    unsigned int u = __float_as_uint(f);
    u += 0x7fffu + ((u >> 16) & 1u);          // round-to-nearest-even
    return (ushort16)(u >> 16);
}
__device__ __forceinline__ float bf_lo(uint32 p) { return __uint_as_float(p << 16); }
__device__ __forceinline__ float bf_hi(uint32 p) { return __uint_as_float(p & 0xffff0000u); }

// ---------------- layer 1 GEMM + logits, fused ------------------------------
// 64 rows/block; thread = 4 rows x 8 cols; x tile staged in LDS (132 pad).
// Epilogue: fp8-e4m3 h1 (8 B uint2 stores) + per-(row,head) attention logits
// computed from the fp32 tile written back into LDS.
__global__ __launch_bounds__(256) void gemm1_kernel(
    const float* __restrict__ x, const float* __restrict__ W,
    uint32* __restrict__ h8,            // fp8 rows, N x 32 dwords
    const float* __restrict__ a_src, const float* __restrict__ a_dst,
    float* __restrict__ ssrc, float* __restrict__ sdst)
{
    __shared__ float xs[64][132];
    const int row0 = blockIdx.x * 64;
    const int tid = threadIdx.x;
#pragma unroll
    for (int i = 0; i < 8; ++i) {
        int idx = tid + i * 256;      // 0..2047
        int r = idx >> 5, c4 = idx & 31;
        float4 v = make_float4(0.f, 0.f, 0.f, 0.f);
        if (row0 + r < N_NODES)
            v = ((const float4*)x)[(size_t)(row0 + r) * 32 + c4];
        *(float4*)&xs[r][c4 * 4] = v;
    }
    __syncthreads();
    const int cg = tid & 15;          // cols 8cg..8cg+7
    const int rg = tid >> 4;          // rows rg+16i, i=0..3
    float acc[4][8];
#pragma unroll
    for (int i = 0; i < 4; ++i)
#pragma unroll
        for (int j = 0; j < 8; ++j) acc[i][j] = 0.f;

    for (int k0 = 0; k0 < 128; k0 += 4) {
        float4 wa[4], wb[4];
#pragma unroll
        for (int kk = 0; kk < 4; ++kk) {
            wa[kk] = ((const float4*)W)[(k0 + kk) * 32 + 2 * cg];
            wb[kk] = ((const float4*)W)[(k0 + kk) * 32 + 2 * cg + 1];
        }
#pragma unroll
        for (int i = 0; i < 4; ++i) {
            float4 hx = *(const float4*)&xs[rg + 16 * i][k0];
            float hv[4] = {hx.x, hx.y, hx.z, hx.w};
#pragma unroll
            for (int kk = 0; kk < 4; ++kk) {
                acc[i][0] = fmaf(hv[kk], wa[kk].x, acc[i][0]);
                acc[i][1] = fmaf(hv[kk], wa[kk].y, acc[i][1]);
                acc[i][2] = fmaf(hv[kk], wa[kk].z, acc[i][2]);
                acc[i][3] = fmaf(hv[kk], wa[kk].w, acc[i][3]);
                acc[i][4] = fmaf(hv[kk], wb[kk].x, acc[i][4]);
                acc[i][5] = fmaf(hv[kk], wb[kk].y, acc[i][5]);
                acc[i][6] = fmaf(hv[kk], wb[kk].z, acc[i][6]);
                acc[i][7] = fmaf(hv[kk], wb[kk].w, acc[i][7]);
            }
        }
    }
    __syncthreads();   // all reads of x tile done
#pragma unroll
    for (int i = 0; i < 4; ++i) {
        int r = rg + 16 * i;
        int p0 = __builtin_amdgcn_cvt_pk_fp8_f32(acc[i][0], acc[i][1], 0, false);
        p0     = __builtin_amdgcn_cvt_pk_fp8_f32(acc[i][2], acc[i][3], p0, true);
        int p1 = __builtin_amdgcn_cvt_pk_fp8_f32(acc[i][4], acc[i][5], 0, false);
        p1     = __builtin_amdgcn_cvt_pk_fp8_f32(acc[i][6], acc[i][7], p1, true);
        if (row0 + r < N_NODES) {
            uint2 pk; pk.x = (uint32)p0; pk.y = (uint32)p1;
            ((uint2*)h8)[(size_t)(row0 + r) * 16 + cg] = pk;
        }
        *(float4*)&xs[r][8 * cg]     = make_float4(acc[i][0], acc[i][1], acc[i][2], acc[i][3]);
        *(float4*)&xs[r][8 * cg + 4] = make_float4(acc[i][4], acc[i][5], acc[i][6], acc[i][7]);
    }
    __syncthreads();
    // logits: 64 rows x 8 heads = 512 tasks, 2 per thread
#pragma unroll
    for (int t = 0; t < 2; ++t) {
        int task = tid + t * 256;
        int r = task >> 3, hh = task & 7;
        if (row0 + r < N_NODES) {
            float as = 0.f, ad = 0.f;
#pragma unroll
            for (int c = 0; c < 16; ++c) {
                float v = xs[r][hh * 16 + c];
                as = fmaf(v, a_src[hh * 16 + c], as);
                ad = fmaf(v, a_dst[hh * 16 + c], ad);
            }
            ssrc[(row0 + r) * 8 + hh] = as;
            sdst[(row0 + r) * 8 + hh] = ad;
        }
    }
}

// ---------------- CSR build: histogram by dst, saving each edge's rank ------
__global__ void count_kernel(const int* __restrict__ ei, int E,
                             int* __restrict__ deg,
                             int* __restrict__ rank)
{
    int e = blockIdx.x * blockDim.x + threadIdx.x;
    if (e < E) rank[e] = atomicAdd(&deg[ei[E + e]], 1);
}

// block-local inclusive scan (256/block) + block sums
__global__ void scan1_kernel(const int* __restrict__ deg,
                             int* __restrict__ incl,
                             int* __restrict__ bsum)
{
    __shared__ int tmp[256];
    int i = blockIdx.x * 256 + threadIdx.x;
    int v = (i < N_NODES) ? deg[i] : 0;
    tmp[threadIdx.x] = v;
    __syncthreads();
    for (int o = 1; o < 256; o <<= 1) {
        int t = (threadIdx.x >= (unsigned)o) ? tmp[threadIdx.x - o] : 0;
        __syncthreads();
        tmp[threadIdx.x] += t;
        __syncthreads();
    }
    if (i < N_NODES) incl[i] = tmp[threadIdx.x];
    if (threadIdx.x == 255) bsum[blockIdx.x] = tmp[255];
}

// exclusive scan of block sums (nb <= 512), single block
__global__ void scan2_kernel(int* __restrict__ bsum, int nb)
{
    __shared__ int tmp[512];
    int v = (threadIdx.x < (unsigned)nb) ? bsum[threadIdx.x] : 0;
    tmp[threadIdx.x] = v;
    __syncthreads();
    for (int o = 1; o < 512; o <<= 1) {
        int t = (threadIdx.x >= (unsigned)o) ? tmp[threadIdx.x - o] : 0;
        __syncthreads();
        tmp[threadIdx.x] += t;
        __syncthreads();
    }
    if (threadIdx.x < (unsigned)nb) bsum[threadIdx.x] = tmp[threadIdx.x] - v;
}

// offsets[i+1] = incl[i] + bsum[block]; offsets[0] = 0
__global__ void scan3_kernel(const int* __restrict__ incl,
                             const int* __restrict__ bsum,
                             int* __restrict__ offsets)
{
    int i = blockIdx.x * 256 + threadIdx.x;
    if (i < N_NODES) offsets[i + 1] = incl[i] + bsum[blockIdx.x];
    if (i == 0) offsets[0] = 0;
}

// atomic-free scatter using precomputed rank
__global__ void scatter_kernel(const int* __restrict__ ei, int E,
                               const int* __restrict__ offsets,
                               const int* __restrict__ rank,
                               int* __restrict__ srcs)
{
    int e = blockIdx.x * blockDim.x + threadIdx.x;
    if (e >= E) return;
    int s = ei[e], d = ei[E + e];
    srcs[offsets[d] + rank[e]] = s;
}

// ---------------- layer 1 gather: one wave per dst node (fp8 h rows) --------
// Weight phase: lane l = (edge l>>3, head l&7). Accumulate phase: two 128-B
// fp8 rows per wave load — half = l>>5 picks edge parity, u = l&31 picks the
// dword (channels 4u..4u+3, head u>>2); cross-half reduce at the end.
__global__ void gather1_kernel(const uint32* __restrict__ h8,   // N x 32 dwords
                               const float* __restrict__ ssrc,
                               const float* __restrict__ sdst,
                               const int* __restrict__ offsets,
                               const int* __restrict__ srcs,
                               const float* __restrict__ b1,
                               float* __restrict__ out)
{
    int d = (blockIdx.x * blockDim.x + threadIdx.x) >> 6;
    int lane = threadIdx.x & 63;
    if (d >= N_NODES) return;
    const int hw = lane & 7;            // head in weight phase
    const int half = lane >> 5;         // edge parity in accumulate phase
    const int u = lane & 31;            // dword in row: channels 4u..4u+3
    const int hc = u >> 2;              // head of my channels
    const float sd_w = sdst[d * H1 + hw];

    float acc0 = 0.f, acc1 = 0.f, acc2 = 0.f, acc3 = 0.f;
    float wsum = 0.f;

    // self-loop weight for my channel head
    float lgs = ssrc[d * H1 + hc] + sdst[d * H1 + hc];
    lgs = lgs >= 0.f ? lgs : NEG * lgs;
    const float ws_self = __expf(lgs);
    {   // only half 0 accumulates the self row (avoid double count)
        float m = (half == 0) ? ws_self : 0.f;
        uint32 p = h8[(size_t)d * 32 + u];
        v2f lo = __builtin_amdgcn_cvt_pk_f32_fp8((int)p, false);
        v2f hi = __builtin_amdgcn_cvt_pk_f32_fp8((int)p, true);
        acc0 = m * lo[0]; acc1 = m * lo[1];
        acc2 = m * hi[0]; acc3 = m * hi[1];
    }

    const int beg = offsets[d], end = offsets[d + 1];
    int base = beg;
    for (; base + 8 <= end; base += 8) {
        int s_l = srcs[base + (lane >> 3)];
        float lg = ssrc[s_l * H1 + hw] + sd_w;
        lg = lg >= 0.f ? lg : NEG * lg;
        float w_l = __expf(lg);
        wsum += w_l;
#pragma unroll
        for (int t = 0; t < 4; ++t) {
            int j = 2 * t + half;
            int s = __shfl(s_l, j << 3);
            float w = __shfl(w_l, (j << 3) | hc);
            uint32 p = h8[(size_t)s * 32 + u];
            v2f lo = __builtin_amdgcn_cvt_pk_f32_fp8((int)p, false);
            v2f hi = __builtin_amdgcn_cvt_pk_f32_fp8((int)p, true);
            acc0 = fmaf(w, lo[0], acc0);
            acc1 = fmaf(w, lo[1], acc1);
            acc2 = fmaf(w, hi[0], acc2);
            acc3 = fmaf(w, hi[1], acc3);
        }
    }
    int cnt = end - base;
    if (cnt > 0) {
        int s_l = 0; float w_l = 0.f;
        if ((lane >> 3) < cnt) {
            s_l = srcs[base + (lane >> 3)];
            float lg = ssrc[s_l * H1 + hw] + sd_w;
            lg = lg >= 0.f ? lg : NEG * lg;
            w_l = __expf(lg);
        }
        wsum += w_l;
        int steps = (cnt + 1) >> 1;
        for (int t = 0; t < steps; ++t) {
            int j = 2 * t + half;        // j may equal cnt (odd tail): w=0 there
            int s = __shfl(s_l, j << 3);
            float w = __shfl(w_l, (j << 3) | hc);
            uint32 p = h8[(size_t)s * 32 + u];
            v2f lo = __builtin_amdgcn_cvt_pk_f32_fp8((int)p, false);
            v2f hi = __builtin_amdgcn_cvt_pk_f32_fp8((int)p, true);
            acc0 = fmaf(w, lo[0], acc0);
            acc1 = fmaf(w, lo[1], acc1);
            acc2 = fmaf(w, hi[0], acc2);
            acc3 = fmaf(w, hi[1], acc3);
        }
    }
    // head-wise total: sum wsum over the 8 edge-slot groups (xor bits 3..5)
    wsum += __shfl_xor(wsum, 8);
    wsum += __shfl_xor(wsum, 16);
    wsum += __shfl_xor(wsum, 32);
    float ws = ws_self + __shfl(wsum, hc);
    // cross-half accumulator reduce
    acc0 += __shfl_xor(acc0, 32);
    acc1 += __shfl_xor(acc1, 32);
    acc2 += __shfl_xor(acc2, 32);
    acc3 += __shfl_xor(acc3, 32);
    if (half == 0) {
        float inv = 1.f / (ws + 1e-16f);
        float4 bb = ((const float4*)b1)[u];
        float4 r;
        r.x = fmaf(acc0, inv, bb.x); r.x = r.x > 0.f ? r.x : 0.f;
        r.y = fmaf(acc1, inv, bb.y); r.y = r.y > 0.f ? r.y : 0.f;
        r.z = fmaf(acc2, inv, bb.z); r.z = r.z > 0.f ? r.z : 0.f;
        r.w = fmaf(acc3, inv, bb.w); r.w = r.w > 0.f ? r.w : 0.f;
        ((float4*)(out + (size_t)d * D1))[u] = r;
    }
}

// ---------------- layer 2 GEMM + logits, fused ------------------------------
__global__ __launch_bounds__(256) void gemm2_kernel(
    const float* __restrict__ h, const float* __restrict__ W2,
    ushort16* __restrict__ h2b,
    const float* __restrict__ a_src, const float* __restrict__ a_dst,
    float* __restrict__ ssrc, float* __restrict__ sdst)
{
    __shared__ float w2s[40][132];
    __shared__ float hs[32][132];
    const int row0 = blockIdx.x * 32;
    const int tid = threadIdx.x;
#pragma unroll
    for (int i = 0; i < 20; ++i) {
        int idx = tid + i * 256;     // 0..5119
        int k = idx / 40, c = idx % 40;
        w2s[c][k] = W2[idx];
    }
#pragma unroll
    for (int i = 0; i < 4; ++i) {
        int idx = tid + i * 256;     // 0..1023
        int r = idx >> 5, c4 = idx & 31;
        *(float4*)&hs[r][c4 * 4] = ((const float4*)h)[(size_t)(row0 + r) * 32 + c4];
    }
    __syncthreads();
    const int rg = tid >> 3;     // row 0..31
    const int g  = tid & 7;      // cols 5g..5g+4
    float acc[5] = {0.f, 0.f, 0.f, 0.f, 0.f};
    for (int k0 = 0; k0 < 128; k0 += 4) {
        float4 hv = *(const float4*)&hs[rg][k0];
#pragma unroll
        for (int j = 0; j < 5; ++j) {
            float4 wv = *(const float4*)&w2s[5 * g + j][k0];
            acc[j] = fmaf(hv.x, wv.x, acc[j]);
            acc[j] = fmaf(hv.y, wv.y, acc[j]);
            acc[j] = fmaf(hv.z, wv.z, acc[j]);
            acc[j] = fmaf(hv.w, wv.w, acc[j]);
        }
    }
#pragma unroll
    for (int j = 0; j < 5; ++j)
        h2b[(size_t)(row0 + rg) * 40 + 5 * g + j] = f2bf(acc[j]);
    __syncthreads();     // all reads of hs done
#pragma unroll
    for (int j = 0; j < 5; ++j)
        hs[rg][5 * g + j] = acc[j];
    __syncthreads();
    if (tid < 32) {
        float as = 0.f, ad = 0.f;
#pragma unroll
        for (int c = 0; c < 40; ++c) {
            float v = hs[tid][c];
            as = fmaf(v, a_src[c], as);
            ad = fmaf(v, a_dst[c], ad);
        }
        ssrc[row0 + tid] = as;
        sdst[row0 + tid] = ad;
    }
}

// ---------------- layer 2 gather + log_softmax: one wave per node (bf16) ----
// Weight phase: 64 edges at a time. MLP phase: 3 lane-groups of 20 stream 3
// rows per load instruction; cross-group reduce at the end.
__global__ void gather2_kernel(const uint32* __restrict__ h2b,  // N x 20 uints
                               const float* __restrict__ ssrc,
                               const float* __restrict__ sdst,
                               const int* __restrict__ offsets,
                               const int* __restrict__ srcs,
                               const float* __restrict__ b2,
                               float* __restrict__ out)
{
    int d = (blockIdx.x * blockDim.x + threadIdx.x) >> 6;
    int lane = threadIdx.x & 63;
    if (d >= N_NODES) return;
    const float sd = sdst[d];
    const int g = lane / 20;              // group 0..2 (3 = idle tail lanes)
    const int c = lane - 20 * g;          // dword within row (channels 2c,2c+1)
    const bool act = lane < (NCLS / 2);   // lanes that own the output
    float acc0 = 0.f, acc1 = 0.f, ws = 0.f;

    // self-loop (group 0 only)
    {
        float lg = ssrc[d] + sd; lg = lg >= 0.f ? lg : NEG * lg;
        float w = __expf(lg);
        uint32 p = act ? h2b[(size_t)d * 20 + lane] : 0u;
        float m = act ? w : 0.f;
        acc0 = m * bf_lo(p); acc1 = m * bf_hi(p);
        ws = w;
    }
    const int beg = offsets[d], end = offsets[d + 1];
    for (int base = beg; base < end; base += 64) {
        int cnt = end - base; if (cnt > 64) cnt = 64;
        int s_l = 0; float w_l = 0.f;
        if (lane < cnt) {
            s_l = srcs[base + lane];
            float lg = ssrc[s_l] + sd; lg = lg >= 0.f ? lg : NEG * lg;
            w_l = __expf(lg);
        }
        float t = w_l;
#pragma unroll
        for (int o = 32; o > 0; o >>= 1) t += __shfl_xor(t, o);
        ws += t;
        for (int j = 0; j < cnt; j += 3) {
            int jj = j + g;
            int s = __shfl(s_l, jj & 63);
            float w = __shfl(w_l, jj & 63);
            if (g >= 3 || jj >= cnt) w = 0.f;
            uint32 p = h2b[(size_t)s * 20 + c];
            acc0 = fmaf(w, bf_lo(p), acc0);
            acc1 = fmaf(w, bf_hi(p), acc1);
        }
    }
    // cross-group reduce: groups live at lanes c, c+20, c+40
    float r00 = __shfl(acc0, lane + 20), r01 = __shfl(acc0, lane + 40);
    float r10 = __shfl(acc1, lane + 20), r11 = __shfl(acc1, lane + 40);
    float l0 = -INFINITY, l1 = -INFINITY;
    if (act) {
        acc0 += r00 + r01;
        acc1 += r10 + r11;
        float inv = 1.f / (ws + 1e-16f);
        l0 = fmaf(acc0, inv, b2[2 * lane]);
        l1 = fmaf(acc1, inv, b2[2 * lane + 1]);
    }
    float m = fmaxf(l0, l1);
#pragma unroll
    for (int o = 32; o > 0; o >>= 1) m = fmaxf(m, __shfl_xor(m, o));
    float ex = act ? (__expf(l0 - m) + __expf(l1 - m)) : 0.f;
#pragma unroll
    for (int o = 32; o > 0; o >>= 1) ex += __shfl_xor(ex, o);
    float lse = __logf(ex) + m;
    if (act) {
        float2 r; r.x = l0 - lse; r.y = l1 - lse;
        ((float2*)(out + (size_t)d * NCLS))[lane] = r;
    }
}

extern "C" void kernel_launch(void* const* d_in, const int* in_sizes, int n_in,
                              void* d_out, int out_size, void* d_ws, size_t ws_size,
                              hipStream_t stream)
{
    const float* x   = (const float*)d_in[0];
    const int*   ei  = (const int*)  d_in[1];
    const float* W1  = (const float*)d_in[2];
    const float* as1 = (const float*)d_in[3];
    const float* ad1 = (const float*)d_in[4];
    const float* b1  = (const float*)d_in[5];
    const float* W2  = (const float*)d_in[6];
    const float* as2 = (const float*)d_in[7];
    const float* ad2 = (const float*)d_in[8];
    const float* b2  = (const float*)d_in[9];
    float* out = (float*)d_out;
    const int E = in_sizes[1] / 2;

    float* ws = (float*)d_ws;
    size_t off = 0;
    uint32* h1f8 = (uint32*)(ws + off); off += (size_t)N_NODES * 32;  // fp8 N x 128
    float* h1r  = ws + off; off += (size_t)N_NODES * D1;
    float* ss1  = ws + off; off += (size_t)N_NODES * H1;
    float* sd1  = ws + off; off += (size_t)N_NODES * H1;
    uint32* h2b = (uint32*)(ws + off); off += (size_t)N_NODES * 20;   // bf16 N x 40
    float* ss2  = ws + off; off += N_NODES;
    float* sd2  = ws + off; off += N_NODES;
    int* ib = (int*)(ws + off);
    size_t ioff = 0;
    int* deg     = ib + ioff; ioff += N_NODES;      // must be zeroed
    int* incl    = ib + ioff; ioff += N_NODES;
    int* offsets = ib + ioff; ioff += N_NODES + 1;
    int* bsum    = ib + ioff; ioff += 512;
    int* rank    = ib + ioff; ioff += E;
    int* srcs    = ib + ioff; ioff += E;

    hipMemsetAsync(deg, 0, (size_t)N_NODES * sizeof(int), stream);

    const int nb = (N_NODES + 255) / 256;           // 391
    // CSR build
    count_kernel<<<(E + 255) / 256, 256, 0, stream>>>(ei, E, deg, rank);
    scan1_kernel<<<nb, 256, 0, stream>>>(deg, incl, bsum);
    scan2_kernel<<<1, 512, 0, stream>>>(bsum, nb);
    scan3_kernel<<<nb, 256, 0, stream>>>(incl, bsum, offsets);
    scatter_kernel<<<(E + 255) / 256, 256, 0, stream>>>(ei, E, offsets, rank, srcs);

    // layer 1 (gemm + logits fused)
    gemm1_kernel<<<(N_NODES + 63) / 64, 256, 0, stream>>>(x, W1, h1f8, as1, ad1, ss1, sd1);
    gather1_kernel<<<(N_NODES * 64 + 255) / 256, 256, 0, stream>>>(h1f8, ss1, sd1, offsets, srcs, b1, h1r);

    // layer 2 (gemm + logits fused)
    gemm2_kernel<<<N_NODES / 32, 256, 0, stream>>>(h1r, W2, (ushort16*)h2b, as2, ad2, ss2, sd2);
    gather2_kernel<<<(N_NODES * 64 + 255) / 256, 256, 0, stream>>>(h2b, ss2, sd2, offsets, srcs, b2, out);
}

// Round 7
// 414.815 us; speedup vs baseline: 32.0027x; 1.0227x over previous
//
#include <hip/hip_runtime.h>
#include <math.h>

#define N_NODES 100000
#define F_IN    128
#define H1      8
#define C1      16
#define D1      128   // H1*C1
#define NCLS    40
#define NEG     0.2f

typedef unsigned int uint32;
typedef unsigned short ushort16;
typedef float v2f __attribute__((ext_vector_type(2)));

__device__ __forceinline__ ushort16 f2bf(float f) {
    unsigned int u = __float_as_uint(f);
    u += 0x7fffu + ((u >> 16) & 1u);          // round-to-nearest-even
    return (ushort16)(u >> 16);
}
__device__ __forceinline__ float bf_lo(uint32 p) { return __uint_as_float(p << 16); }
__device__ __forceinline__ float bf_hi(uint32 p) { return __uint_as_float(p & 0xffff0000u); }

// ---------------- layer 1 GEMM + logits, fused ------------------------------
// 64 rows/block. W staged in LDS transposed (two 64-k chunks, stride 68:
// b128 reads along k, 2-way bank aliasing = free). Thread = (cg 0..15,
// rg 0..15): rows rg+16i, cols cg+16j. Epilogue: acc -> xs (fp32), repack
// fp8-e4m3 rows + per-(row,head) attention logits from xs.
__global__ __launch_bounds__(256) void gemm1_kernel(
    const float* __restrict__ x, const float* __restrict__ W,
    uint32* __restrict__ h8,            // fp8 rows, N x 32 dwords
    const float* __restrict__ a_src, const float* __restrict__ a_dst,
    float* __restrict__ ssrc, float* __restrict__ sdst)
{
    __shared__ float xs[64][132];       // x tile (fp32), later h1 tile
    __shared__ float wt[128][68];       // W chunk transposed: wt[col][k]
    const int row0 = blockIdx.x * 64;
    const int tid = threadIdx.x;
    // ---- load x tile (coalesced float4) ----
#pragma unroll
    for (int i = 0; i < 8; ++i) {
        int idx = tid + i * 256;      // 0..2047
        int r = idx >> 5, c4 = idx & 31;
        float4 v = make_float4(0.f, 0.f, 0.f, 0.f);
        if (row0 + r < N_NODES)
            v = ((const float4*)x)[(size_t)(row0 + r) * 32 + c4];
        *(float4*)&xs[r][c4 * 4] = v;
    }
    const int cg = tid & 15;
    const int rg = tid >> 4;
    float acc[4][8];
#pragma unroll
    for (int i = 0; i < 4; ++i)
#pragma unroll
        for (int j = 0; j < 8; ++j) acc[i][j] = 0.f;

    const int stc = tid & 127;        // staging: col
    const int sth = tid >> 7;         // staging: k-half (0..1)
#pragma unroll
    for (int chunk = 0; chunk < 2; ++chunk) {
        const int kbase = chunk * 64;
        __syncthreads();              // wt free / x tile ready
        // ---- stage W[kbase..kbase+63][*] transposed into wt ----
#pragma unroll
        for (int kk = 0; kk < 8; ++kk) {
            int k = sth * 32 + kk * 4;
            float4 v;
            v.x = W[(size_t)(kbase + k)     * 128 + stc];
            v.y = W[(size_t)(kbase + k + 1) * 128 + stc];
            v.z = W[(size_t)(kbase + k + 2) * 128 + stc];
            v.w = W[(size_t)(kbase + k + 3) * 128 + stc];
            *(float4*)&wt[stc][k] = v;
        }
        __syncthreads();
        // ---- K-loop over this chunk ----
        for (int k0 = 0; k0 < 64; k0 += 4) {
            float4 wa[8];
#pragma unroll
            for (int j = 0; j < 8; ++j)
                wa[j] = *(const float4*)&wt[cg + 16 * j][k0];
#pragma unroll
            for (int i = 0; i < 4; ++i) {
                float4 hx = *(const float4*)&xs[rg + 16 * i][kbase + k0];
#pragma unroll
                for (int j = 0; j < 8; ++j) {
                    acc[i][j] = fmaf(hx.x, wa[j].x, acc[i][j]);
                    acc[i][j] = fmaf(hx.y, wa[j].y, acc[i][j]);
                    acc[i][j] = fmaf(hx.z, wa[j].z, acc[i][j]);
                    acc[i][j] = fmaf(hx.w, wa[j].w, acc[i][j]);
                }
            }
        }
    }
    __syncthreads();   // all reads of x tile done
    // ---- write h1 (fp32) back into xs ----
#pragma unroll
    for (int i = 0; i < 4; ++i)
#pragma unroll
        for (int j = 0; j < 8; ++j)
            xs[rg + 16 * i][cg + 16 * j] = acc[i][j];
    __syncthreads();
    // ---- fp8 pack: 64 rows x 16 uint2-groups, 4 tasks/thread ----
#pragma unroll
    for (int t = 0; t < 4; ++t) {
        int task = tid + t * 256;     // 0..1023
        int r = task >> 4, g = task & 15;
        if (row0 + r < N_NODES) {
            float4 a = *(const float4*)&xs[r][8 * g];
            float4 b = *(const float4*)&xs[r][8 * g + 4];
            int p0 = __builtin_amdgcn_cvt_pk_fp8_f32(a.x, a.y, 0, false);
            p0     = __builtin_amdgcn_cvt_pk_fp8_f32(a.z, a.w, p0, true);
            int p1 = __builtin_amdgcn_cvt_pk_fp8_f32(b.x, b.y, 0, false);
            p1     = __builtin_amdgcn_cvt_pk_fp8_f32(b.z, b.w, p1, true);
            uint2 pk; pk.x = (uint32)p0; pk.y = (uint32)p1;
            ((uint2*)h8)[(size_t)(row0 + r) * 16 + g] = pk;
        }
    }
    // ---- logits: 64 rows x 8 heads = 512 tasks, 2 per thread ----
#pragma unroll
    for (int t = 0; t < 2; ++t) {
        int task = tid + t * 256;
        int r = task >> 3, hh = task & 7;
        if (row0 + r < N_NODES) {
            float as = 0.f, ad = 0.f;
#pragma unroll
            for (int c = 0; c < 16; ++c) {
                float v = xs[r][hh * 16 + c];
                as = fmaf(v, a_src[hh * 16 + c], as);
                ad = fmaf(v, a_dst[hh * 16 + c], ad);
            }
            ssrc[(row0 + r) * 8 + hh] = as;
            sdst[(row0 + r) * 8 + hh] = ad;
        }
    }
}

// ---------------- CSR build: histogram by dst, saving each edge's rank ------
__global__ void count_kernel(const int* __restrict__ ei, int E,
                             int* __restrict__ deg,
                             int* __restrict__ rank)
{
    int e = blockIdx.x * blockDim.x + threadIdx.x;
    if (e < E) rank[e] = atomicAdd(&deg[ei[E + e]], 1);
}

// block-local inclusive scan (256/block) + block sums
__global__ void scan1_kernel(const int* __restrict__ deg,
                             int* __restrict__ incl,
                             int* __restrict__ bsum)
{
    __shared__ int tmp[256];
    int i = blockIdx.x * 256 + threadIdx.x;
    int v = (i < N_NODES) ? deg[i] : 0;
    tmp[threadIdx.x] = v;
    __syncthreads();
    for (int o = 1; o < 256; o <<= 1) {
        int t = (threadIdx.x >= (unsigned)o) ? tmp[threadIdx.x - o] : 0;
        __syncthreads();
        tmp[threadIdx.x] += t;
        __syncthreads();
    }
    if (i < N_NODES) incl[i] = tmp[threadIdx.x];
    if (threadIdx.x == 255) bsum[blockIdx.x] = tmp[255];
}

// exclusive scan of block sums (nb <= 512), single block
__global__ void scan2_kernel(int* __restrict__ bsum, int nb)
{
    __shared__ int tmp[512];
    int v = (threadIdx.x < (unsigned)nb) ? bsum[threadIdx.x] : 0;
    tmp[threadIdx.x] = v;
    __syncthreads();
    for (int o = 1; o < 512; o <<= 1) {
        int t = (threadIdx.x >= (unsigned)o) ? tmp[threadIdx.x - o] : 0;
        __syncthreads();
        tmp[threadIdx.x] += t;
        __syncthreads();
    }
    if (threadIdx.x < (unsigned)nb) bsum[threadIdx.x] = tmp[threadIdx.x] - v;
}

// offsets[i+1] = incl[i] + bsum[block]; offsets[0] = 0
__global__ void scan3_kernel(const int* __restrict__ incl,
                             const int* __restrict__ bsum,
                             int* __restrict__ offsets)
{
    int i = blockIdx.x * 256 + threadIdx.x;
    if (i < N_NODES) offsets[i + 1] = incl[i] + bsum[blockIdx.x];
    if (i == 0) offsets[0] = 0;
}

// atomic-free scatter using precomputed rank
__global__ void scatter_kernel(const int* __restrict__ ei, int E,
                               const int* __restrict__ offsets,
                               const int* __restrict__ rank,
                               int* __restrict__ srcs)
{
    int e = blockIdx.x * blockDim.x + threadIdx.x;
    if (e >= E) return;
    int s = ei[e], d = ei[E + e];
    srcs[offsets[d] + rank[e]] = s;
}

// ---------------- layer 1 gather: one wave per dst node (fp8 h rows) --------
__global__ void gather1_kernel(const uint32* __restrict__ h8,   // N x 32 dwords
                               const float* __restrict__ ssrc,
                               const float* __restrict__ sdst,
                               const int* __restrict__ offsets,
                               const int* __restrict__ srcs,
                               const float* __restrict__ b1,
                               float* __restrict__ out)
{
    int d = (blockIdx.x * blockDim.x + threadIdx.x) >> 6;
    int lane = threadIdx.x & 63;
    if (d >= N_NODES) return;
    const int hw = lane & 7;            // head in weight phase
    const int half = lane >> 5;         // edge parity in accumulate phase
    const int u = lane & 31;            // dword in row: channels 4u..4u+3
    const int hc = u >> 2;              // head of my channels
    const float sd_w = sdst[d * H1 + hw];

    float acc0 = 0.f, acc1 = 0.f, acc2 = 0.f, acc3 = 0.f;
    float wsum = 0.f;

    // self-loop weight for my channel head
    float lgs = ssrc[d * H1 + hc] + sdst[d * H1 + hc];
    lgs = lgs >= 0.f ? lgs : NEG * lgs;
    const float ws_self = __expf(lgs);
    {   // only half 0 accumulates the self row (avoid double count)
        float m = (half == 0) ? ws_self : 0.f;
        uint32 p = h8[(size_t)d * 32 + u];
        v2f lo = __builtin_amdgcn_cvt_pk_f32_fp8((int)p, false);
        v2f hi = __builtin_amdgcn_cvt_pk_f32_fp8((int)p, true);
        acc0 = m * lo[0]; acc1 = m * lo[1];
        acc2 = m * hi[0]; acc3 = m * hi[1];
    }

    const int beg = offsets[d], end = offsets[d + 1];
    int base = beg;
    for (; base + 8 <= end; base += 8) {
        int s_l = srcs[base + (lane >> 3)];
        float lg = ssrc[s_l * H1 + hw] + sd_w;
        lg = lg >= 0.f ? lg : NEG * lg;
        float w_l = __expf(lg);
        wsum += w_l;
#pragma unroll
        for (int t = 0; t < 4; ++t) {
            int j = 2 * t + half;
            int s = __shfl(s_l, j << 3);
            float w = __shfl(w_l, (j << 3) | hc);
            uint32 p = h8[(size_t)s * 32 + u];
            v2f lo = __builtin_amdgcn_cvt_pk_f32_fp8((int)p, false);
            v2f hi = __builtin_amdgcn_cvt_pk_f32_fp8((int)p, true);
            acc0 = fmaf(w, lo[0], acc0);
            acc1 = fmaf(w, lo[1], acc1);
            acc2 = fmaf(w, hi[0], acc2);
            acc3 = fmaf(w, hi[1], acc3);
        }
    }
    int cnt = end - base;
    if (cnt > 0) {
        int s_l = 0; float w_l = 0.f;
        if ((lane >> 3) < cnt) {
            s_l = srcs[base + (lane >> 3)];
            float lg = ssrc[s_l * H1 + hw] + sd_w;
            lg = lg >= 0.f ? lg : NEG * lg;
            w_l = __expf(lg);
        }
        wsum += w_l;
        int steps = (cnt + 1) >> 1;
        for (int t = 0; t < steps; ++t) {
            int j = 2 * t + half;        // j may equal cnt (odd tail): w=0 there
            int s = __shfl(s_l, j << 3);
            float w = __shfl(w_l, (j << 3) | hc);
            uint32 p = h8[(size_t)s * 32 + u];
            v2f lo = __builtin_amdgcn_cvt_pk_f32_fp8((int)p, false);
            v2f hi = __builtin_amdgcn_cvt_pk_f32_fp8((int)p, true);
            acc0 = fmaf(w, lo[0], acc0);
            acc1 = fmaf(w, lo[1], acc1);
            acc2 = fmaf(w, hi[0], acc2);
            acc3 = fmaf(w, hi[1], acc3);
        }
    }
    // head-wise total: sum wsum over the 8 edge-slot groups (xor bits 3..5)
    wsum += __shfl_xor(wsum, 8);
    wsum += __shfl_xor(wsum, 16);
    wsum += __shfl_xor(wsum, 32);
    float ws = ws_self + __shfl(wsum, hc);
    // cross-half accumulator reduce
    acc0 += __shfl_xor(acc0, 32);
    acc1 += __shfl_xor(acc1, 32);
    acc2 += __shfl_xor(acc2, 32);
    acc3 += __shfl_xor(acc3, 32);
    if (half == 0) {
        float inv = 1.f / (ws + 1e-16f);
        float4 bb = ((const float4*)b1)[u];
        float4 r;
        r.x = fmaf(acc0, inv, bb.x); r.x = r.x > 0.f ? r.x : 0.f;
        r.y = fmaf(acc1, inv, bb.y); r.y = r.y > 0.f ? r.y : 0.f;
        r.z = fmaf(acc2, inv, bb.z); r.z = r.z > 0.f ? r.z : 0.f;
        r.w = fmaf(acc3, inv, bb.w); r.w = r.w > 0.f ? r.w : 0.f;
        ((float4*)(out + (size_t)d * D1))[u] = r;
    }
}

// ---------------- layer 2 GEMM + logits, fused ------------------------------
__global__ __launch_bounds__(256) void gemm2_kernel(
    const float* __restrict__ h, const float* __restrict__ W2,
    ushort16* __restrict__ h2b,
    const float* __restrict__ a_src, const float* __restrict__ a_dst,
    float* __restrict__ ssrc, float* __restrict__ sdst)
{
    __shared__ float w2s[40][132];
    __shared__ float hs[32][132];
    const int row0 = blockIdx.x * 32;
    const int tid = threadIdx.x;
#pragma unroll
    for (int i = 0; i < 20; ++i) {
        int idx = tid + i * 256;     // 0..5119
        int k = idx / 40, c = idx % 40;
        w2s[c][k] = W2[idx];
    }
#pragma unroll
    for (int i = 0; i < 4; ++i) {
        int idx = tid + i * 256;     // 0..1023
        int r = idx >> 5, c4 = idx & 31;
        *(float4*)&hs[r][c4 * 4] = ((const float4*)h)[(size_t)(row0 + r) * 32 + c4];
    }
    __syncthreads();
    const int rg = tid >> 3;     // row 0..31
    const int g  = tid & 7;      // cols 5g..5g+4
    float acc[5] = {0.f, 0.f, 0.f, 0.f, 0.f};
    for (int k0 = 0; k0 < 128; k0 += 4) {
        float4 hv = *(const float4*)&hs[rg][k0];
#pragma unroll
        for (int j = 0; j < 5; ++j) {
            float4 wv = *(const float4*)&w2s[5 * g + j][k0];
            acc[j] = fmaf(hv.x, wv.x, acc[j]);
            acc[j] = fmaf(hv.y, wv.y, acc[j]);
            acc[j] = fmaf(hv.z, wv.z, acc[j]);
            acc[j] = fmaf(hv.w, wv.w, acc[j]);
        }
    }
#pragma unroll
    for (int j = 0; j < 5; ++j)
        h2b[(size_t)(row0 + rg) * 40 + 5 * g + j] = f2bf(acc[j]);
    __syncthreads();     // all reads of hs done
#pragma unroll
    for (int j = 0; j < 5; ++j)
        hs[rg][5 * g + j] = acc[j];
    __syncthreads();
    if (tid < 32) {
        float as = 0.f, ad = 0.f;
#pragma unroll
        for (int c = 0; c < 40; ++c) {
            float v = hs[tid][c];
            as = fmaf(v, a_src[c], as);
            ad = fmaf(v, a_dst[c], ad);
        }
        ssrc[row0 + tid] = as;
        sdst[row0 + tid] = ad;
    }
}

// ---------------- layer 2 gather + log_softmax: one wave per node (bf16) ----
__global__ void gather2_kernel(const uint32* __restrict__ h2b,  // N x 20 uints
                               const float* __restrict__ ssrc,
                               const float* __restrict__ sdst,
                               const int* __restrict__ offsets,
                               const int* __restrict__ srcs,
                               const float* __restrict__ b2,
                               float* __restrict__ out)
{
    int d = (blockIdx.x * blockDim.x + threadIdx.x) >> 6;
    int lane = threadIdx.x & 63;
    if (d >= N_NODES) return;
    const float sd = sdst[d];
    const int g = lane / 20;              // group 0..2 (3 = idle tail lanes)
    const int c = lane - 20 * g;          // dword within row (channels 2c,2c+1)
    const bool act = lane < (NCLS / 2);   // lanes that own the output
    float acc0 = 0.f, acc1 = 0.f, ws = 0.f;

    // self-loop (group 0 only)
    {
        float lg = ssrc[d] + sd; lg = lg >= 0.f ? lg : NEG * lg;
        float w = __expf(lg);
        uint32 p = act ? h2b[(size_t)d * 20 + lane] : 0u;
        float m = act ? w : 0.f;
        acc0 = m * bf_lo(p); acc1 = m * bf_hi(p);
        ws = w;
    }
    const int beg = offsets[d], end = offsets[d + 1];
    for (int base = beg; base < end; base += 64) {
        int cnt = end - base; if (cnt > 64) cnt = 64;
        int s_l = 0; float w_l = 0.f;
        if (lane < cnt) {
            s_l = srcs[base + lane];
            float lg = ssrc[s_l] + sd; lg = lg >= 0.f ? lg : NEG * lg;
            w_l = __expf(lg);
        }
        float t = w_l;
#pragma unroll
        for (int o = 32; o > 0; o >>= 1) t += __shfl_xor(t, o);
        ws += t;
        for (int j = 0; j < cnt; j += 3) {
            int jj = j + g;
            int s = __shfl(s_l, jj & 63);
            float w = __shfl(w_l, jj & 63);
            if (g >= 3 || jj >= cnt) w = 0.f;
            uint32 p = h2b[(size_t)s * 20 + c];
            acc0 = fmaf(w, bf_lo(p), acc0);
            acc1 = fmaf(w, bf_hi(p), acc1);
        }
    }
    // cross-group reduce: groups live at lanes c, c+20, c+40
    float r00 = __shfl(acc0, lane + 20), r01 = __shfl(acc0, lane + 40);
    float r10 = __shfl(acc1, lane + 20), r11 = __shfl(acc1, lane + 40);
    float l0 = -INFINITY, l1 = -INFINITY;
    if (act) {
        acc0 += r00 + r01;
        acc1 += r10 + r11;
        float inv = 1.f / (ws + 1e-16f);
        l0 = fmaf(acc0, inv, b2[2 * lane]);
        l1 = fmaf(acc1, inv, b2[2 * lane + 1]);
    }
    float m = fmaxf(l0, l1);
#pragma unroll
    for (int o = 32; o > 0; o >>= 1) m = fmaxf(m, __shfl_xor(m, o));
    float ex = act ? (__expf(l0 - m) + __expf(l1 - m)) : 0.f;
#pragma unroll
    for (int o = 32; o > 0; o >>= 1) ex += __shfl_xor(ex, o);
    float lse = __logf(ex) + m;
    if (act) {
        float2 r; r.x = l0 - lse; r.y = l1 - lse;
        ((float2*)(out + (size_t)d * NCLS))[lane] = r;
    }
}

extern "C" void kernel_launch(void* const* d_in, const int* in_sizes, int n_in,
                              void* d_out, int out_size, void* d_ws, size_t ws_size,
                              hipStream_t stream)
{
    const float* x   = (const float*)d_in[0];
    const int*   ei  = (const int*)  d_in[1];
    const float* W1  = (const float*)d_in[2];
    const float* as1 = (const float*)d_in[3];
    const float* ad1 = (const float*)d_in[4];
    const float* b1  = (const float*)d_in[5];
    const float* W2  = (const float*)d_in[6];
    const float* as2 = (const float*)d_in[7];
    const float* ad2 = (const float*)d_in[8];
    const float* b2  = (const float*)d_in[9];
    float* out = (float*)d_out;
    const int E = in_sizes[1] / 2;

    float* ws = (float*)d_ws;
    size_t off = 0;
    uint32* h1f8 = (uint32*)(ws + off); off += (size_t)N_NODES * 32;  // fp8 N x 128
    float* h1r  = ws + off; off += (size_t)N_NODES * D1;
    float* ss1  = ws + off; off += (size_t)N_NODES * H1;
    float* sd1  = ws + off; off += (size_t)N_NODES * H1;
    uint32* h2b = (uint32*)(ws + off); off += (size_t)N_NODES * 20;   // bf16 N x 40
    float* ss2  = ws + off; off += N_NODES;
    float* sd2  = ws + off; off += N_NODES;
    int* ib = (int*)(ws + off);
    size_t ioff = 0;
    int* deg     = ib + ioff; ioff += N_NODES;      // must be zeroed
    int* incl    = ib + ioff; ioff += N_NODES;
    int* offsets = ib + ioff; ioff += N_NODES + 1;
    int* bsum    = ib + ioff; ioff += 512;
    int* rank    = ib + ioff; ioff += E;
    int* srcs    = ib + ioff; ioff += E;

    hipMemsetAsync(deg, 0, (size_t)N_NODES * sizeof(int), stream);

    const int nb = (N_NODES + 255) / 256;           // 391
    // CSR build
    count_kernel<<<(E + 255) / 256, 256, 0, stream>>>(ei, E, deg, rank);
    scan1_kernel<<<nb, 256, 0, stream>>>(deg, incl, bsum);
    scan2_kernel<<<1, 512, 0, stream>>>(bsum, nb);
    scan3_kernel<<<nb, 256, 0, stream>>>(incl, bsum, offsets);
    scatter_kernel<<<(E + 255) / 256, 256, 0, stream>>>(ei, E, offsets, rank, srcs);

    // layer 1 (gemm + logits fused)
    gemm1_kernel<<<(N_NODES + 63) / 64, 256, 0, stream>>>(x, W1, h1f8, as1, ad1, ss1, sd1);
    gather1_kernel<<<(N_NODES * 64 + 255) / 256, 256, 0, stream>>>(h1f8, ss1, sd1, offsets, srcs, b1, h1r);

    // layer 2 (gemm + logits fused)
    gemm2_kernel<<<N_NODES / 32, 256, 0, stream>>>(h1r, W2, (ushort16*)h2b, as2, ad2, ss2, sd2);
    gather2_kernel<<<(N_NODES * 64 + 255) / 256, 256, 0, stream>>>(h2b, ss2, sd2, offsets, srcs, b2, out);
}

// Round 8
// 386.734 us; speedup vs baseline: 34.3264x; 1.0726x over previous
//
#include <hip/hip_runtime.h>
#include <math.h>

#define N_NODES 100000
#define F_IN    128
#define H1      8
#define C1      16
#define D1      128   // H1*C1
#define NCLS    40
#define NEG     0.2f

typedef unsigned int uint32;
typedef unsigned short ushort16;
typedef float v2f __attribute__((ext_vector_type(2)));

__device__ __forceinline__ ushort16 f2bf(float f) {
    unsigned int u = __float_as_uint(f);
    u += 0x7fffu + ((u >> 16) & 1u);          // round-to-nearest-even
    return (ushort16)(u >> 16);
}
__device__ __forceinline__ float bf_lo(uint32 p) { return __uint_as_float(p << 16); }
__device__ __forceinline__ float bf_hi(uint32 p) { return __uint_as_float(p & 0xffff0000u); }

#define NG 1563   // gemm blocks (64 rows each)

// ---------------- fused: layer-1 GEMM(+logits) blocks + CSR-count blocks ----
// Interleave 1:4 (gemm at blockIdx%5==0) so LDS-pipe-bound gemm blocks and
// fabric-atomic-bound count blocks are co-resident on every CU from t=0.
__global__ __launch_bounds__(256) void gemm1_count_kernel(
    const float* __restrict__ x, const float* __restrict__ W,
    uint32* __restrict__ h8,            // fp8 rows, N x 32 dwords
    const float* __restrict__ a_src, const float* __restrict__ a_dst,
    float* __restrict__ ssrc, float* __restrict__ sdst,
    const int* __restrict__ ei, int E,
    int* __restrict__ deg, int* __restrict__ rank)
{
    __shared__ float xs[64][132];       // x tile (fp32), later h1 tile
    __shared__ float wt[128][68];       // W chunk transposed: wt[col][k]
    const int bid = blockIdx.x;
    const int tid = threadIdx.x;
    const bool is_gemm = ((bid % 5) == 0) && (bid / 5 < NG);
    if (!is_gemm) {
        // ---------------- count path: rank[e] = old deg[dst]++ ----------------
        int ng_before = bid / 5 + ((bid % 5) ? 1 : 0);   // gemm blocks with id < bid
        if (ng_before > NG) ng_before = NG;
        int c = bid - ng_before;
        long long e = (long long)c * 256 + tid;
        if (e < E) rank[e] = atomicAdd(&deg[ei[E + e]], 1);
        return;
    }
    const int row0 = (bid / 5) * 64;
    // ---- load x tile (coalesced float4) ----
#pragma unroll
    for (int i = 0; i < 8; ++i) {
        int idx = tid + i * 256;      // 0..2047
        int r = idx >> 5, c4 = idx & 31;
        float4 v = make_float4(0.f, 0.f, 0.f, 0.f);
        if (row0 + r < N_NODES)
            v = ((const float4*)x)[(size_t)(row0 + r) * 32 + c4];
        *(float4*)&xs[r][c4 * 4] = v;
    }
    const int cg = tid & 15;
    const int rg = tid >> 4;
    float acc[4][8];
#pragma unroll
    for (int i = 0; i < 4; ++i)
#pragma unroll
        for (int j = 0; j < 8; ++j) acc[i][j] = 0.f;

    const int stc = tid & 127;        // staging: col
    const int sth = tid >> 7;         // staging: k-half (0..1)
#pragma unroll
    for (int chunk = 0; chunk < 2; ++chunk) {
        const int kbase = chunk * 64;
        __syncthreads();              // wt free / x tile ready
#pragma unroll
        for (int kk = 0; kk < 8; ++kk) {
            int k = sth * 32 + kk * 4;
            float4 v;
            v.x = W[(size_t)(kbase + k)     * 128 + stc];
            v.y = W[(size_t)(kbase + k + 1) * 128 + stc];
            v.z = W[(size_t)(kbase + k + 2) * 128 + stc];
            v.w = W[(size_t)(kbase + k + 3) * 128 + stc];
            *(float4*)&wt[stc][k] = v;
        }
        __syncthreads();
        for (int k0 = 0; k0 < 64; k0 += 4) {
            float4 wa[8];
#pragma unroll
            for (int j = 0; j < 8; ++j)
                wa[j] = *(const float4*)&wt[cg + 16 * j][k0];
#pragma unroll
            for (int i = 0; i < 4; ++i) {
                float4 hx = *(const float4*)&xs[rg + 16 * i][kbase + k0];
#pragma unroll
                for (int j = 0; j < 8; ++j) {
                    acc[i][j] = fmaf(hx.x, wa[j].x, acc[i][j]);
                    acc[i][j] = fmaf(hx.y, wa[j].y, acc[i][j]);
                    acc[i][j] = fmaf(hx.z, wa[j].z, acc[i][j]);
                    acc[i][j] = fmaf(hx.w, wa[j].w, acc[i][j]);
                }
            }
        }
    }
    __syncthreads();   // all reads of x tile done
    // ---- write h1 (fp32) back into xs ----
#pragma unroll
    for (int i = 0; i < 4; ++i)
#pragma unroll
        for (int j = 0; j < 8; ++j)
            xs[rg + 16 * i][cg + 16 * j] = acc[i][j];
    __syncthreads();
    // ---- fp8 pack: 64 rows x 16 uint2-groups, 4 tasks/thread ----
#pragma unroll
    for (int t = 0; t < 4; ++t) {
        int task = tid + t * 256;     // 0..1023
        int r = task >> 4, g = task & 15;
        if (row0 + r < N_NODES) {
            float4 a = *(const float4*)&xs[r][8 * g];
            float4 b = *(const float4*)&xs[r][8 * g + 4];
            int p0 = __builtin_amdgcn_cvt_pk_fp8_f32(a.x, a.y, 0, false);
            p0     = __builtin_amdgcn_cvt_pk_fp8_f32(a.z, a.w, p0, true);
            int p1 = __builtin_amdgcn_cvt_pk_fp8_f32(b.x, b.y, 0, false);
            p1     = __builtin_amdgcn_cvt_pk_fp8_f32(b.z, b.w, p1, true);
            uint2 pk; pk.x = (uint32)p0; pk.y = (uint32)p1;
            ((uint2*)h8)[(size_t)(row0 + r) * 16 + g] = pk;
        }
    }
    // ---- logits: 64 rows x 8 heads = 512 tasks, 2 per thread ----
#pragma unroll
    for (int t = 0; t < 2; ++t) {
        int task = tid + t * 256;
        int r = task >> 3, hh = task & 7;
        if (row0 + r < N_NODES) {
            float as = 0.f, ad = 0.f;
#pragma unroll
            for (int c = 0; c < 16; ++c) {
                float v = xs[r][hh * 16 + c];
                as = fmaf(v, a_src[hh * 16 + c], as);
                ad = fmaf(v, a_dst[hh * 16 + c], ad);
            }
            ssrc[(row0 + r) * 8 + hh] = as;
            sdst[(row0 + r) * 8 + hh] = ad;
        }
    }
}

// block-local inclusive scan (256/block) + block sums
__global__ void scan1_kernel(const int* __restrict__ deg,
                             int* __restrict__ incl,
                             int* __restrict__ bsum)
{
    __shared__ int tmp[256];
    int i = blockIdx.x * 256 + threadIdx.x;
    int v = (i < N_NODES) ? deg[i] : 0;
    tmp[threadIdx.x] = v;
    __syncthreads();
    for (int o = 1; o < 256; o <<= 1) {
        int t = (threadIdx.x >= (unsigned)o) ? tmp[threadIdx.x - o] : 0;
        __syncthreads();
        tmp[threadIdx.x] += t;
        __syncthreads();
    }
    if (i < N_NODES) incl[i] = tmp[threadIdx.x];
    if (threadIdx.x == 255) bsum[blockIdx.x] = tmp[255];
}

// exclusive scan of block sums (nb <= 512), single block
__global__ void scan2_kernel(int* __restrict__ bsum, int nb)
{
    __shared__ int tmp[512];
    int v = (threadIdx.x < (unsigned)nb) ? bsum[threadIdx.x] : 0;
    tmp[threadIdx.x] = v;
    __syncthreads();
    for (int o = 1; o < 512; o <<= 1) {
        int t = (threadIdx.x >= (unsigned)o) ? tmp[threadIdx.x - o] : 0;
        __syncthreads();
        tmp[threadIdx.x] += t;
        __syncthreads();
    }
    if (threadIdx.x < (unsigned)nb) bsum[threadIdx.x] = tmp[threadIdx.x] - v;
}

// offsets[i+1] = incl[i] + bsum[block]; offsets[0] = 0
__global__ void scan3_kernel(const int* __restrict__ incl,
                             const int* __restrict__ bsum,
                             int* __restrict__ offsets)
{
    int i = blockIdx.x * 256 + threadIdx.x;
    if (i < N_NODES) offsets[i + 1] = incl[i] + bsum[blockIdx.x];
    if (i == 0) offsets[0] = 0;
}

// atomic-free scatter using precomputed rank
__global__ void scatter_kernel(const int* __restrict__ ei, int E,
                               const int* __restrict__ offsets,
                               const int* __restrict__ rank,
                               int* __restrict__ srcs)
{
    int e = blockIdx.x * blockDim.x + threadIdx.x;
    if (e >= E) return;
    int s = ei[e], d = ei[E + e];
    srcs[offsets[d] + rank[e]] = s;
}

// ---------------- layer 1 gather: one wave per dst node (fp8 h rows) --------
__global__ void gather1_kernel(const uint32* __restrict__ h8,   // N x 32 dwords
                               const float* __restrict__ ssrc,
                               const float* __restrict__ sdst,
                               const int* __restrict__ offsets,
                               const int* __restrict__ srcs,
                               const float* __restrict__ b1,
                               float* __restrict__ out)
{
    int d = (blockIdx.x * blockDim.x + threadIdx.x) >> 6;
    int lane = threadIdx.x & 63;
    if (d >= N_NODES) return;
    const int hw = lane & 7;            // head in weight phase
    const int half = lane >> 5;         // edge parity in accumulate phase
    const int u = lane & 31;            // dword in row: channels 4u..4u+3
    const int hc = u >> 2;              // head of my channels
    const float sd_w = sdst[d * H1 + hw];

    float acc0 = 0.f, acc1 = 0.f, acc2 = 0.f, acc3 = 0.f;
    float wsum = 0.f;

    // self-loop weight for my channel head
    float lgs = ssrc[d * H1 + hc] + sdst[d * H1 + hc];
    lgs = lgs >= 0.f ? lgs : NEG * lgs;
    const float ws_self = __expf(lgs);
    {   // only half 0 accumulates the self row (avoid double count)
        float m = (half == 0) ? ws_self : 0.f;
        uint32 p = h8[(size_t)d * 32 + u];
        v2f lo = __builtin_amdgcn_cvt_pk_f32_fp8((int)p, false);
        v2f hi = __builtin_amdgcn_cvt_pk_f32_fp8((int)p, true);
        acc0 = m * lo[0]; acc1 = m * lo[1];
        acc2 = m * hi[0]; acc3 = m * hi[1];
    }

    const int beg = offsets[d], end = offsets[d + 1];
    int base = beg;
    for (; base + 8 <= end; base += 8) {
        int s_l = srcs[base + (lane >> 3)];
        float lg = ssrc[s_l * H1 + hw] + sd_w;
        lg = lg >= 0.f ? lg : NEG * lg;
        float w_l = __expf(lg);
        wsum += w_l;
#pragma unroll
        for (int t = 0; t < 4; ++t) {
            int j = 2 * t + half;
            int s = __shfl(s_l, j << 3);
            float w = __shfl(w_l, (j << 3) | hc);
            uint32 p = h8[(size_t)s * 32 + u];
            v2f lo = __builtin_amdgcn_cvt_pk_f32_fp8((int)p, false);
            v2f hi = __builtin_amdgcn_cvt_pk_f32_fp8((int)p, true);
            acc0 = fmaf(w, lo[0], acc0);
            acc1 = fmaf(w, lo[1], acc1);
            acc2 = fmaf(w, hi[0], acc2);
            acc3 = fmaf(w, hi[1], acc3);
        }
    }
    int cnt = end - base;
    if (cnt > 0) {
        int s_l = 0; float w_l = 0.f;
        if ((lane >> 3) < cnt) {
            s_l = srcs[base + (lane >> 3)];
            float lg = ssrc[s_l * H1 + hw] + sd_w;
            lg = lg >= 0.f ? lg : NEG * lg;
            w_l = __expf(lg);
        }
        wsum += w_l;
        int steps = (cnt + 1) >> 1;
        for (int t = 0; t < steps; ++t) {
            int j = 2 * t + half;        // j may equal cnt (odd tail): w=0 there
            int s = __shfl(s_l, j << 3);
            float w = __shfl(w_l, (j << 3) | hc);
            uint32 p = h8[(size_t)s * 32 + u];
            v2f lo = __builtin_amdgcn_cvt_pk_f32_fp8((int)p, false);
            v2f hi = __builtin_amdgcn_cvt_pk_f32_fp8((int)p, true);
            acc0 = fmaf(w, lo[0], acc0);
            acc1 = fmaf(w, lo[1], acc1);
            acc2 = fmaf(w, hi[0], acc2);
            acc3 = fmaf(w, hi[1], acc3);
        }
    }
    // head-wise total: sum wsum over the 8 edge-slot groups (xor bits 3..5)
    wsum += __shfl_xor(wsum, 8);
    wsum += __shfl_xor(wsum, 16);
    wsum += __shfl_xor(wsum, 32);
    float ws = ws_self + __shfl(wsum, hc);
    // cross-half accumulator reduce
    acc0 += __shfl_xor(acc0, 32);
    acc1 += __shfl_xor(acc1, 32);
    acc2 += __shfl_xor(acc2, 32);
    acc3 += __shfl_xor(acc3, 32);
    if (half == 0) {
        float inv = 1.f / (ws + 1e-16f);
        float4 bb = ((const float4*)b1)[u];
        float4 r;
        r.x = fmaf(acc0, inv, bb.x); r.x = r.x > 0.f ? r.x : 0.f;
        r.y = fmaf(acc1, inv, bb.y); r.y = r.y > 0.f ? r.y : 0.f;
        r.z = fmaf(acc2, inv, bb.z); r.z = r.z > 0.f ? r.z : 0.f;
        r.w = fmaf(acc3, inv, bb.w); r.w = r.w > 0.f ? r.w : 0.f;
        ((float4*)(out + (size_t)d * D1))[u] = r;
    }
}

// ---------------- layer 2 GEMM + logits, fused ------------------------------
// 64 rows/block, thread = 2 rows (rr, rr+32) x 5 cols: 7 ds_read_b128 per
// 40 FMAs (was 6 per 20) -> ~halves LDS-pipe time. Bank-checked conflict-free.
__global__ __launch_bounds__(256) void gemm2_kernel(
    const float* __restrict__ h, const float* __restrict__ W2,
    ushort16* __restrict__ h2b,
    const float* __restrict__ a_src, const float* __restrict__ a_dst,
    float* __restrict__ ssrc, float* __restrict__ sdst)
{
    __shared__ float w2s[40][132];
    __shared__ float hs[64][132];
    const int row0 = blockIdx.x * 64;
    const int tid = threadIdx.x;
#pragma unroll
    for (int i = 0; i < 20; ++i) {
        int idx = tid + i * 256;     // 0..5119
        int k = idx / 40, c = idx % 40;
        w2s[c][k] = W2[idx];
    }
#pragma unroll
    for (int i = 0; i < 8; ++i) {
        int idx = tid + i * 256;     // 0..2047
        int r = idx >> 5, c4 = idx & 31;
        float4 v = make_float4(0.f, 0.f, 0.f, 0.f);
        if (row0 + r < N_NODES)
            v = ((const float4*)h)[(size_t)(row0 + r) * 32 + c4];
        *(float4*)&hs[r][c4 * 4] = v;
    }
    __syncthreads();
    const int rr = tid >> 3;     // row pair (rr, rr+32)
    const int g  = tid & 7;      // cols 5g..5g+4
    float acc[2][5];
#pragma unroll
    for (int t = 0; t < 2; ++t)
#pragma unroll
        for (int j = 0; j < 5; ++j) acc[t][j] = 0.f;
    for (int k0 = 0; k0 < 128; k0 += 4) {
        float4 ha = *(const float4*)&hs[rr][k0];
        float4 hb = *(const float4*)&hs[rr + 32][k0];
#pragma unroll
        for (int j = 0; j < 5; ++j) {
            float4 wv = *(const float4*)&w2s[5 * g + j][k0];
            acc[0][j] = fmaf(ha.x, wv.x, acc[0][j]);
            acc[0][j] = fmaf(ha.y, wv.y, acc[0][j]);
            acc[0][j] = fmaf(ha.z, wv.z, acc[0][j]);
            acc[0][j] = fmaf(ha.w, wv.w, acc[0][j]);
            acc[1][j] = fmaf(hb.x, wv.x, acc[1][j]);
            acc[1][j] = fmaf(hb.y, wv.y, acc[1][j]);
            acc[1][j] = fmaf(hb.z, wv.z, acc[1][j]);
            acc[1][j] = fmaf(hb.w, wv.w, acc[1][j]);
        }
    }
#pragma unroll
    for (int t = 0; t < 2; ++t) {
        int row = row0 + rr + 32 * t;
        if (row < N_NODES) {
#pragma unroll
            for (int j = 0; j < 5; ++j)
                h2b[(size_t)row * 40 + 5 * g + j] = f2bf(acc[t][j]);
        }
    }
    __syncthreads();     // all reads of hs done
#pragma unroll
    for (int t = 0; t < 2; ++t)
#pragma unroll
        for (int j = 0; j < 5; ++j)
            hs[rr + 32 * t][5 * g + j] = acc[t][j];
    __syncthreads();
    if (tid < 64 && row0 + tid < N_NODES) {
        float as = 0.f, ad = 0.f;
#pragma unroll
        for (int c = 0; c < 40; ++c) {
            float v = hs[tid][c];
            as = fmaf(v, a_src[c], as);
            ad = fmaf(v, a_dst[c], ad);
        }
        ssrc[row0 + tid] = as;
        sdst[row0 + tid] = ad;
    }
}

// ---------------- layer 2 gather + log_softmax: one wave per node (bf16) ----
__global__ void gather2_kernel(const uint32* __restrict__ h2b,  // N x 20 uints
                               const float* __restrict__ ssrc,
                               const float* __restrict__ sdst,
                               const int* __restrict__ offsets,
                               const int* __restrict__ srcs,
                               const float* __restrict__ b2,
                               float* __restrict__ out)
{
    int d = (blockIdx.x * blockDim.x + threadIdx.x) >> 6;
    int lane = threadIdx.x & 63;
    if (d >= N_NODES) return;
    const float sd = sdst[d];
    const int g = lane / 20;              // group 0..2 (3 = idle tail lanes)
    const int c = lane - 20 * g;          // dword within row (channels 2c,2c+1)
    const bool act = lane < (NCLS / 2);   // lanes that own the output
    float acc0 = 0.f, acc1 = 0.f, ws = 0.f;

    // self-loop (group 0 only)
    {
        float lg = ssrc[d] + sd; lg = lg >= 0.f ? lg : NEG * lg;
        float w = __expf(lg);
        uint32 p = act ? h2b[(size_t)d * 20 + lane] : 0u;
        float m = act ? w : 0.f;
        acc0 = m * bf_lo(p); acc1 = m * bf_hi(p);
        ws = w;
    }
    const int beg = offsets[d], end = offsets[d + 1];
    for (int base = beg; base < end; base += 64) {
        int cnt = end - base; if (cnt > 64) cnt = 64;
        int s_l = 0; float w_l = 0.f;
        if (lane < cnt) {
            s_l = srcs[base + lane];
            float lg = ssrc[s_l] + sd; lg = lg >= 0.f ? lg : NEG * lg;
            w_l = __expf(lg);
        }
        float t = w_l;
#pragma unroll
        for (int o = 32; o > 0; o >>= 1) t += __shfl_xor(t, o);
        ws += t;
        for (int j = 0; j < cnt; j += 3) {
            int jj = j + g;
            int s = __shfl(s_l, jj & 63);
            float w = __shfl(w_l, jj & 63);
            if (g >= 3 || jj >= cnt) w = 0.f;
            uint32 p = h2b[(size_t)s * 20 + c];
            acc0 = fmaf(w, bf_lo(p), acc0);
            acc1 = fmaf(w, bf_hi(p), acc1);
        }
    }
    // cross-group reduce: groups live at lanes c, c+20, c+40
    float r00 = __shfl(acc0, lane + 20), r01 = __shfl(acc0, lane + 40);
    float r10 = __shfl(acc1, lane + 20), r11 = __shfl(acc1, lane + 40);
    float l0 = -INFINITY, l1 = -INFINITY;
    if (act) {
        acc0 += r00 + r01;
        acc1 += r10 + r11;
        float inv = 1.f / (ws + 1e-16f);
        l0 = fmaf(acc0, inv, b2[2 * lane]);
        l1 = fmaf(acc1, inv, b2[2 * lane + 1]);
    }
    float m = fmaxf(l0, l1);
#pragma unroll
    for (int o = 32; o > 0; o >>= 1) m = fmaxf(m, __shfl_xor(m, o));
    float ex = act ? (__expf(l0 - m) + __expf(l1 - m)) : 0.f;
#pragma unroll
    for (int o = 32; o > 0; o >>= 1) ex += __shfl_xor(ex, o);
    float lse = __logf(ex) + m;
    if (act) {
        float2 r; r.x = l0 - lse; r.y = l1 - lse;
        ((float2*)(out + (size_t)d * NCLS))[lane] = r;
    }
}

extern "C" void kernel_launch(void* const* d_in, const int* in_sizes, int n_in,
                              void* d_out, int out_size, void* d_ws, size_t ws_size,
                              hipStream_t stream)
{
    const float* x   = (const float*)d_in[0];
    const int*   ei  = (const int*)  d_in[1];
    const float* W1  = (const float*)d_in[2];
    const float* as1 = (const float*)d_in[3];
    const float* ad1 = (const float*)d_in[4];
    const float* b1  = (const float*)d_in[5];
    const float* W2  = (const float*)d_in[6];
    const float* as2 = (const float*)d_in[7];
    const float* ad2 = (const float*)d_in[8];
    const float* b2  = (const float*)d_in[9];
    float* out = (float*)d_out;
    const int E = in_sizes[1] / 2;

    float* ws = (float*)d_ws;
    size_t off = 0;
    uint32* h1f8 = (uint32*)(ws + off); off += (size_t)N_NODES * 32;  // fp8 N x 128
    float* h1r  = ws + off; off += (size_t)N_NODES * D1;
    float* ss1  = ws + off; off += (size_t)N_NODES * H1;
    float* sd1  = ws + off; off += (size_t)N_NODES * H1;
    uint32* h2b = (uint32*)(ws + off); off += (size_t)N_NODES * 20;   // bf16 N x 40
    float* ss2  = ws + off; off += N_NODES;
    float* sd2  = ws + off; off += N_NODES;
    int* ib = (int*)(ws + off);
    size_t ioff = 0;
    int* deg     = ib + ioff; ioff += N_NODES;      // must be zeroed
    int* incl    = ib + ioff; ioff += N_NODES;
    int* offsets = ib + ioff; ioff += N_NODES + 1;
    int* bsum    = ib + ioff; ioff += 512;
    int* rank    = ib + ioff; ioff += E;
    int* srcs    = ib + ioff; ioff += E;

    hipMemsetAsync(deg, 0, (size_t)N_NODES * sizeof(int), stream);

    const int nb = (N_NODES + 255) / 256;           // 391
    const int nc = (E + 255) / 256;                 // count blocks (6250)

    // fused layer-1 gemm(+logits) + CSR count
    gemm1_count_kernel<<<NG + nc, 256, 0, stream>>>(x, W1, h1f8, as1, ad1,
                                                    ss1, sd1, ei, E, deg, rank);
    // CSR finish
    scan1_kernel<<<nb, 256, 0, stream>>>(deg, incl, bsum);
    scan2_kernel<<<1, 512, 0, stream>>>(bsum, nb);
    scan3_kernel<<<nb, 256, 0, stream>>>(incl, bsum, offsets);
    scatter_kernel<<<(E + 255) / 256, 256, 0, stream>>>(ei, E, offsets, rank, srcs);

    // layer 1 gather
    gather1_kernel<<<(N_NODES * 64 + 255) / 256, 256, 0, stream>>>(h1f8, ss1, sd1, offsets, srcs, b1, h1r);

    // layer 2 (gemm + logits fused)
    gemm2_kernel<<<(N_NODES + 63) / 64, 256, 0, stream>>>(h1r, W2, (ushort16*)h2b, as2, ad2, ss2, sd2);
    gather2_kernel<<<(N_NODES * 64 + 255) / 256, 256, 0, stream>>>(h2b, ss2, sd2, offsets, srcs, b2, out);
}